// Round 1
// baseline (334.945 us; speedup 1.0000x reference)
//
#include <hip/hip_runtime.h>
#include <hip/hip_bf16.h>

typedef _Float16 f16;
typedef __attribute__((ext_vector_type(8))) _Float16 f16x8;
typedef __attribute__((ext_vector_type(4))) _Float16 f16x4;
typedef __attribute__((ext_vector_type(4))) float f32x4;

#define MFMA16(a, b, c) __builtin_amdgcn_mfma_f32_16x16x32_f16(a, b, c, 0, 0, 0)

// ---------------- fp32 -> f16 convert (vectorized) ----------------
__global__ __launch_bounds__(256) void cvt_kernel(const float* __restrict__ in, f16* __restrict__ out, int n4)
{
    int i = blockIdx.x * 256 + threadIdx.x;
    if (i >= n4) return;
    float4 v = ((const float4*)in)[i];
    f16x4 o;
    o[0] = (f16)v.x; o[1] = (f16)v.y; o[2] = (f16)v.z; o[3] = (f16)v.w;
    *(f16x4*)(out + 4 * (size_t)i) = o;
}

// ---------------- RoPE tables, double precision ----------------
__global__ __launch_bounds__(256) void tables_kernel(float* __restrict__ cost, float* __restrict__ sint)
{
    int idx = blockIdx.x * 256 + threadIdx.x;
    if (idx >= 2048 * 32) return;
    int t = idx >> 5, i = idx & 31;
    double invf = pow(10000.0, -(double)(2 * i) / 64.0);
    double a = (double)t * invf;
    cost[idx] = (float)cos(a);
    sint[idx] = (float)sin(a);
}

// ---------------- RoPE apply: in [B*T, Hn*64] -> out [B, Hn, T, 64] ----------------
__global__ __launch_bounds__(256) void rope_kernel(const f16* __restrict__ in, f16* __restrict__ out,
                                                   const float* __restrict__ cost, const float* __restrict__ sint,
                                                   int Hn)
{
    int idx = blockIdx.x * 256 + threadIdx.x;
    if (idx >= 2 * 2048 * Hn) return;
    int h = idx % Hn; int bt = idx / Hn; int t = bt & 2047; int b = bt >> 11;
    const f16* row = in + ((size_t)bt * Hn + h) * 64;
    f16* orow = out + (((size_t)(b * Hn + h)) * 2048 + t) * 64;
#pragma unroll
    for (int i = 0; i < 32; ++i) {
        float c = cost[t * 32 + i], s = sint[t * 32 + i];
        float x1 = (float)row[i], x2 = (float)row[i + 32];
        orow[i]      = (f16)(x1 * c - x2 * s);
        orow[i + 32] = (f16)(x2 * c + x1 * s);
    }
}

// ---------------- f16 GEMM: C[M,N] = A[M,K] @ B[K,N] ----------------
// BM=128 fixed, 256 threads = 4 waves in 2x2, wave tile 64 x BN/2, BK=32.
template<int BN, bool OUTF>
__global__ __launch_bounds__(256) void gemm_f16(const f16* __restrict__ A, const f16* __restrict__ B,
                                                void* __restrict__ Cv, int M, int N, int K)
{
    constexpr int BM = 128, BK = 32, LDP = BK + 8;  // 40 f16 rows = 80B, 16B-aligned, 2-way-free banks
    constexpr int FM = 4, FN = BN / 32;
    __shared__ f16 As[BM][LDP];
    __shared__ f16 Bs[BN][LDP];   // stored transposed: Bs[n][k]
    int tid = threadIdx.x, lane = tid & 63, wid = tid >> 6;
    int wr = wid >> 1, wc = wid & 1;
    int row0 = blockIdx.y * BM, col0 = blockIdx.x * BN;
    int lrow = lane & 15, lk = (lane >> 4) * 8;
    f32x4 acc[FM][FN];
#pragma unroll
    for (int a = 0; a < FM; ++a)
#pragma unroll
        for (int bb = 0; bb < FN; ++bb) acc[a][bb] = (f32x4){0.f, 0.f, 0.f, 0.f};

    int ar = tid >> 2, ac = (tid & 3) * 8;          // A staging: rows ar, ar+64; cols ac..ac+8
    constexpr int TPR = BN / 8;                     // B staging threads per k-row
    int kr = tid / TPR, c8 = (tid % TPR) * 8;

    for (int k0 = 0; k0 < K; k0 += BK) {
        f16x8 av0 = *(const f16x8*)&A[(size_t)(row0 + ar) * K + k0 + ac];
        f16x8 av1 = *(const f16x8*)&A[(size_t)(row0 + ar + 64) * K + k0 + ac];
        *(f16x8*)&As[ar][ac] = av0;
        *(f16x8*)&As[ar + 64][ac] = av1;
#pragma unroll
        for (int kk = kr; kk < BK; kk += 256 / TPR) {
            f16x8 bv = *(const f16x8*)&B[(size_t)(k0 + kk) * N + col0 + c8];
#pragma unroll
            for (int j = 0; j < 8; ++j) Bs[c8 + j][kk] = bv[j];
        }
        __syncthreads();
        f16x8 af[FM], bfr[FN];
#pragma unroll
        for (int fm = 0; fm < FM; ++fm) af[fm] = *(const f16x8*)&As[wr * 64 + fm * 16 + lrow][lk];
#pragma unroll
        for (int fn = 0; fn < FN; ++fn) bfr[fn] = *(const f16x8*)&Bs[wc * (BN / 2) + fn * 16 + lrow][lk];
#pragma unroll
        for (int fm = 0; fm < FM; ++fm)
#pragma unroll
            for (int fn = 0; fn < FN; ++fn)
                acc[fm][fn] = MFMA16(af[fm], bfr[fn], acc[fm][fn]);
        __syncthreads();
    }
    // epilogue: C/D layout col=lane&15, row=(lane>>4)*4+reg
#pragma unroll
    for (int fm = 0; fm < FM; ++fm)
#pragma unroll
        for (int fn = 0; fn < FN; ++fn)
#pragma unroll
            for (int r = 0; r < 4; ++r) {
                int row = row0 + wr * 64 + fm * 16 + (lane >> 4) * 4 + r;
                int col = col0 + wc * (BN / 2) + fn * 16 + lrow;
                if (OUTF) ((float*)Cv)[(size_t)row * N + col] = acc[fm][fn][r];
                else      ((f16*)Cv)[(size_t)row * N + col] = (f16)acc[fm][fn][r];
            }
}

// ---------------- causal MQA flash attention ----------------
// q: [B,H,T,64] (rope'd), k: [B,T,64] (rope'd), v: [B,T,64]; ao: [B*T, 1024] (h-major cols)
// grid (T/64, B*H); block 256 = 4 waves; each wave owns 16 q rows; K/V tiles of 64 staged in LDS.
__global__ __launch_bounds__(256) void attn_kernel(const f16* __restrict__ q, const f16* __restrict__ k,
                                                   const f16* __restrict__ v, f16* __restrict__ ao)
{
    constexpr int T = 2048, D = 64;
    int qt = blockIdx.x, bh = blockIdx.y;
    int b = bh >> 4, h = bh & 15;
    int tid = threadIdx.x, lane = tid & 63, wid = tid >> 6;
    int lrow = lane & 15, g = lane >> 4;
    int q0 = qt * 64, qw = q0 + wid * 16;
    const f16* qptr = q + ((size_t)bh * T + qw) * D;
    const f16* kptr = k + (size_t)b * T * D;
    const f16* vptr = v + (size_t)b * T * D;
    __shared__ f16 Ks[64][72];      // [krow][d], 144B rows: aligned + conflict-free b128
    __shared__ f16 Vt[64][72];      // transposed: [d][krow]
    __shared__ f16 Ps[4][16][72];   // per-wave P tile [qrow][kcol]

    f16x8 qf0 = *(const f16x8*)&qptr[lrow * D + g * 8];
    f16x8 qf1 = *(const f16x8*)&qptr[lrow * D + 32 + g * 8];
    float m[4] = {-1e30f, -1e30f, -1e30f, -1e30f};
    float l[4] = {0.f, 0.f, 0.f, 0.f};
    f32x4 o[4];
#pragma unroll
    for (int dt = 0; dt < 4; ++dt) o[dt] = (f32x4){0.f, 0.f, 0.f, 0.f};

    int sr = tid >> 2, sc = (tid & 3) * 8;  // staging assignment
    int nkt = qt + 1;                        // causal: only tiles with k <= q0+63
    for (int kt = 0; kt < nkt; ++kt) {
        const f16* kb = kptr + (size_t)kt * 64 * D;
        const f16* vb = vptr + (size_t)kt * 64 * D;
        *(f16x8*)&Ks[sr][sc]      = *(const f16x8*)&kb[sr * D + sc];
        *(f16x8*)&Ks[sr][sc + 32] = *(const f16x8*)&kb[sr * D + sc + 32];
        f16x8 v0 = *(const f16x8*)&vb[sr * D + sc];
        f16x8 v1 = *(const f16x8*)&vb[sr * D + sc + 32];
#pragma unroll
        for (int j = 0; j < 8; ++j) { Vt[sc + j][sr] = v0[j]; Vt[sc + 32 + j][sr] = v1[j]; }
        __syncthreads();

        // S = Q K^T  (A=Q frags, B=K rows read contiguous-in-d)
        f32x4 s[4];
#pragma unroll
        for (int t = 0; t < 4; ++t) {
            f16x8 kf0 = *(const f16x8*)&Ks[t * 16 + lrow][g * 8];
            f16x8 kf1 = *(const f16x8*)&Ks[t * 16 + lrow][32 + g * 8];
            f32x4 z = (f32x4){0.f, 0.f, 0.f, 0.f};
            z = MFMA16(qf0, kf0, z);
            z = MFMA16(qf1, kf1, z);
            s[t] = z;
        }
        // online softmax; lane holds rows g*4+rr, cols t*16+lrow
#pragma unroll
        for (int rr = 0; rr < 4; ++rr) {
            int qab = qw + g * 4 + rr;
            float mx = -1e30f;
#pragma unroll
            for (int t = 0; t < 4; ++t) {
                int kab = kt * 64 + t * 16 + lrow;
                float sv = s[t][rr] * 0.125f;
                sv = (kab > qab) ? -1e30f : sv;
                s[t][rr] = sv;
                mx = fmaxf(mx, sv);
            }
#pragma unroll
            for (int off = 1; off < 16; off <<= 1) mx = fmaxf(mx, __shfl_xor(mx, off));
            float mn = fmaxf(m[rr], mx);
            float alpha = __expf(m[rr] - mn);
            float rs = 0.f;
#pragma unroll
            for (int t = 0; t < 4; ++t) {
                float p = __expf(s[t][rr] - mn);
                s[t][rr] = p;
                rs += p;
            }
#pragma unroll
            for (int off = 1; off < 16; off <<= 1) rs += __shfl_xor(rs, off);
            l[rr] = l[rr] * alpha + rs;
            m[rr] = mn;
#pragma unroll
            for (int dt = 0; dt < 4; ++dt) o[dt][rr] *= alpha;
        }
        // P -> per-wave LDS (D-layout -> A-layout round trip)
#pragma unroll
        for (int t = 0; t < 4; ++t)
#pragma unroll
            for (int rr = 0; rr < 4; ++rr)
                Ps[wid][g * 4 + rr][t * 16 + lrow] = (f16)s[t][rr];
        __syncthreads();
        f16x8 pf0 = *(const f16x8*)&Ps[wid][lrow][g * 8];
        f16x8 pf1 = *(const f16x8*)&Ps[wid][lrow][32 + g * 8];
#pragma unroll
        for (int dt = 0; dt < 4; ++dt) {
            f16x8 vf0 = *(const f16x8*)&Vt[dt * 16 + lrow][g * 8];
            f16x8 vf1 = *(const f16x8*)&Vt[dt * 16 + lrow][32 + g * 8];
            o[dt] = MFMA16(pf0, vf0, o[dt]);
            o[dt] = MFMA16(pf1, vf1, o[dt]);
        }
        __syncthreads();
    }
    // epilogue: divide by l, write [b*T+q, h*64+d]
#pragma unroll
    for (int dt = 0; dt < 4; ++dt)
#pragma unroll
        for (int rr = 0; rr < 4; ++rr) {
            int qab = qw + g * 4 + rr;
            float oo = o[dt][rr] / l[rr];
            ao[((size_t)(b * T + qab)) * 1024 + h * 64 + dt * 16 + lrow] = (f16)oo;
        }
}

extern "C" void kernel_launch(void* const* d_in, const int* in_sizes, int n_in,
                              void* d_out, int out_size, void* d_ws, size_t ws_size,
                              hipStream_t stream)
{
    (void)in_sizes; (void)n_in; (void)out_size; (void)ws_size;
    const float* x  = (const float*)d_in[0];
    const float* Wq = (const float*)d_in[1];
    const float* Wk = (const float*)d_in[2];
    const float* Wv = (const float*)d_in[3];
    const float* Wo = (const float*)d_in[4];
    float* out = (float*)d_out;

    // B=2, T=2048, C=1024, H=16, D=64; M = B*T = 4096
    char* w = (char*)d_ws;
    size_t off = 0;
    auto alloc = [&](size_t bytes) -> void* {
        void* p = (void*)(w + off);
        off += (bytes + 255) & ~(size_t)255;
        return p;
    };
    f16* xb   = (f16*)alloc(4194304ull * 2);  // [4096,1024]
    f16* Wqb  = (f16*)alloc(1048576ull * 2);
    f16* Wkb  = (f16*)alloc(65536ull * 2);
    f16* Wvb  = (f16*)alloc(65536ull * 2);
    f16* Wob  = (f16*)alloc(1048576ull * 2);
    f16* qg   = (f16*)alloc(4194304ull * 2);  // q gemm out [4096,1024]
    f16* kg   = (f16*)alloc(262144ull * 2);   // [4096,64]
    f16* vg   = (f16*)alloc(262144ull * 2);
    f16* qr   = (f16*)alloc(4194304ull * 2);  // rope'd q [B,H,T,64]
    f16* krp  = (f16*)alloc(262144ull * 2);   // rope'd k [B,T,64]
    float* cost = (float*)alloc(65536ull * 4);
    float* sint = (float*)alloc(65536ull * 4);
    f16* ao = qg;  // alias: qg is dead after rope

    // converts
    cvt_kernel<<<4096, 256, 0, stream>>>(x,  xb,  1048576);
    cvt_kernel<<<1024, 256, 0, stream>>>(Wq, Wqb, 262144);
    cvt_kernel<<<64,   256, 0, stream>>>(Wk, Wkb, 16384);
    cvt_kernel<<<64,   256, 0, stream>>>(Wv, Wvb, 16384);
    cvt_kernel<<<1024, 256, 0, stream>>>(Wo, Wob, 262144);
    tables_kernel<<<256, 256, 0, stream>>>(cost, sint);

    // projections
    gemm_f16<128, false><<<dim3(8, 32), 256, 0, stream>>>(xb, Wqb, qg, 4096, 1024, 1024);
    gemm_f16<64,  false><<<dim3(1, 32), 256, 0, stream>>>(xb, Wkb, kg, 4096, 64, 1024);
    gemm_f16<64,  false><<<dim3(1, 32), 256, 0, stream>>>(xb, Wvb, vg, 4096, 64, 1024);

    // rope
    rope_kernel<<<256, 256, 0, stream>>>(qg, qr, cost, sint, 16);
    rope_kernel<<<16,  256, 0, stream>>>(kg, krp, cost, sint, 1);

    // attention
    attn_kernel<<<dim3(32, 32), 256, 0, stream>>>(qr, krp, vg, ao);

    // output projection (fp32 out)
    gemm_f16<128, true><<<dim3(8, 32), 256, 0, stream>>>(ao, Wob, out, 4096, 1024, 1024);
}

// Round 2
// 306.240 us; speedup vs baseline: 1.0937x; 1.0937x over previous
//
#include <hip/hip_runtime.h>
#include <hip/hip_bf16.h>

typedef _Float16 f16;
typedef __attribute__((ext_vector_type(8))) _Float16 f16x8;
typedef __attribute__((ext_vector_type(4))) _Float16 f16x4;
typedef __attribute__((ext_vector_type(4))) float f32x4;

#define MFMA16(a, b, c) __builtin_amdgcn_mfma_f32_16x16x32_f16(a, b, c, 0, 0, 0)

// ---------------- fp32 -> f16 convert (vectorized) ----------------
__global__ __launch_bounds__(256) void cvt_kernel(const float* __restrict__ in, f16* __restrict__ out, int n4)
{
    int i = blockIdx.x * 256 + threadIdx.x;
    if (i >= n4) return;
    float4 v = ((const float4*)in)[i];
    f16x4 o;
    o[0] = (f16)v.x; o[1] = (f16)v.y; o[2] = (f16)v.z; o[3] = (f16)v.w;
    *(f16x4*)(out + 4 * (size_t)i) = o;
}

// ---------------- Wk|Wv fused convert -> [1024][128] ----------------
__global__ __launch_bounds__(256) void cvt_kv_kernel(const float* __restrict__ Wk, const float* __restrict__ Wv,
                                                     f16* __restrict__ out)
{
    int i = blockIdx.x * 256 + threadIdx.x;   // f32x4 index over [1024][128]
    if (i >= 32768) return;
    int col = (i & 31) * 4;
    int row = i >> 5;
    float4 v = (col < 64) ? ((const float4*)(Wk + (size_t)row * 64 + col))[0]
                          : ((const float4*)(Wv + (size_t)row * 64 + col - 64))[0];
    f16x4 o;
    o[0] = (f16)v.x; o[1] = (f16)v.y; o[2] = (f16)v.z; o[3] = (f16)v.w;
    *(f16x4*)(out + 4 * (size_t)i) = o;
}

// ---------------- RoPE tables, double precision ----------------
__global__ __launch_bounds__(256) void tables_kernel(float* __restrict__ cost, float* __restrict__ sint)
{
    int idx = blockIdx.x * 256 + threadIdx.x;
    if (idx >= 2048 * 32) return;
    int t = idx >> 5, i = idx & 31;
    double invf = pow(10000.0, -(double)(2 * i) / 64.0);
    double a = (double)t * invf;
    cost[idx] = (float)cos(a);
    sint[idx] = (float)sin(a);
}

// ---------------- f16 GEMM: C[M,N] = A[M,K] @ B[K,N] ----------------
// BM=128 fixed, 256 threads = 4 waves in 2x2, wave tile 64 x BN/2, BK=32.
// MODE 0: f16 C out. MODE 1: f32 C out. MODE 2: N=128 KV mode -> rope'd K to kout[.,64], V to vout[.,64].
template<int BN, int MODE>
__global__ __launch_bounds__(256) void gemm_f16(const f16* __restrict__ A, const f16* __restrict__ B,
                                                void* __restrict__ Cv, f16* __restrict__ kout, f16* __restrict__ vout,
                                                const float* __restrict__ cost, const float* __restrict__ sint,
                                                int M, int N, int K)
{
    constexpr int BM = 128, BK = 32, LDP = BK + 8;
    constexpr int FM = 4, FN = BN / 32;
    __shared__ f16 As[BM][LDP];
    __shared__ f16 Bs[BN][LDP];   // stored transposed: Bs[n][k]
    int tid = threadIdx.x, lane = tid & 63, wid = tid >> 6;
    int wr = wid >> 1, wc = wid & 1;
    int row0 = blockIdx.y * BM, col0 = blockIdx.x * BN;
    int lrow = lane & 15, lk = (lane >> 4) * 8;
    f32x4 acc[FM][FN];
#pragma unroll
    for (int a = 0; a < FM; ++a)
#pragma unroll
        for (int bb = 0; bb < FN; ++bb) acc[a][bb] = (f32x4){0.f, 0.f, 0.f, 0.f};

    int ar = tid >> 2, ac = (tid & 3) * 8;
    constexpr int TPR = BN / 8;
    int kr = tid / TPR, c8 = (tid % TPR) * 8;

    for (int k0 = 0; k0 < K; k0 += BK) {
        f16x8 av0 = *(const f16x8*)&A[(size_t)(row0 + ar) * K + k0 + ac];
        f16x8 av1 = *(const f16x8*)&A[(size_t)(row0 + ar + 64) * K + k0 + ac];
        *(f16x8*)&As[ar][ac] = av0;
        *(f16x8*)&As[ar + 64][ac] = av1;
#pragma unroll
        for (int kk = kr; kk < BK; kk += 256 / TPR) {
            f16x8 bv = *(const f16x8*)&B[(size_t)(k0 + kk) * N + col0 + c8];
#pragma unroll
            for (int j = 0; j < 8; ++j) Bs[c8 + j][kk] = bv[j];
        }
        __syncthreads();
        f16x8 af[FM], bfr[FN];
#pragma unroll
        for (int fm = 0; fm < FM; ++fm) af[fm] = *(const f16x8*)&As[wr * 64 + fm * 16 + lrow][lk];
#pragma unroll
        for (int fn = 0; fn < FN; ++fn) bfr[fn] = *(const f16x8*)&Bs[wc * (BN / 2) + fn * 16 + lrow][lk];
#pragma unroll
        for (int fm = 0; fm < FM; ++fm)
#pragma unroll
            for (int fn = 0; fn < FN; ++fn)
                acc[fm][fn] = MFMA16(af[fm], bfr[fn], acc[fm][fn]);
        __syncthreads();
    }
    // epilogue: C/D layout col=lane&15, row=(lane>>4)*4+reg
    if constexpr (MODE == 2) {
        // wc==0 waves own cols 0..63 = K head (rope); wc==1 own cols 64..127 = V head
#pragma unroll
        for (int fm = 0; fm < FM; ++fm)
#pragma unroll
            for (int r = 0; r < 4; ++r) {
                int row = row0 + wr * 64 + fm * 16 + (lane >> 4) * 4 + r;
                int t = row & 2047;
                if (wc == 0) {
#pragma unroll
                    for (int fn = 0; fn < 2; ++fn) {
                        int i = fn * 16 + lrow;
                        float c = cost[t * 32 + i], s = sint[t * 32 + i];
                        float x0 = acc[fm][fn][r], x1 = acc[fm][fn + 2][r];
                        kout[(size_t)row * 64 + i]      = (f16)(x0 * c - x1 * s);
                        kout[(size_t)row * 64 + i + 32] = (f16)(x1 * c + x0 * s);
                    }
                } else {
#pragma unroll
                    for (int fn = 0; fn < FN; ++fn)
                        vout[(size_t)row * 64 + fn * 16 + lrow] = (f16)acc[fm][fn][r];
                }
            }
    } else {
#pragma unroll
        for (int fm = 0; fm < FM; ++fm)
#pragma unroll
            for (int fn = 0; fn < FN; ++fn)
#pragma unroll
                for (int r = 0; r < 4; ++r) {
                    int row = row0 + wr * 64 + fm * 16 + (lane >> 4) * 4 + r;
                    int col = col0 + wc * (BN / 2) + fn * 16 + lrow;
                    if (MODE == 1) ((float*)Cv)[(size_t)row * N + col] = acc[fm][fn][r];
                    else           ((f16*)Cv)[(size_t)row * N + col] = (f16)acc[fm][fn][r];
                }
    }
}

// ---------------- causal MQA flash attention, KVBLK=128, fused Q-RoPE ----------------
// q: [B*T, 1024] (raw proj, h-major), k: [B*T,64] rope'd, v: [B*T,64]; ao: [B*T, 1024]
// grid (T/64, B*H); block 256 = 4 waves; wave owns 16 q rows.
__global__ __launch_bounds__(256) void attn_kernel(const f16* __restrict__ q, const f16* __restrict__ k,
                                                   const f16* __restrict__ v, f16* __restrict__ ao,
                                                   const float* __restrict__ cost, const float* __restrict__ sint)
{
    constexpr int T = 2048;
    int qt = blockIdx.x, bh = blockIdx.y;
    int b = bh >> 4, h = bh & 15;
    int tid = threadIdx.x, lane = tid & 63, wid = tid >> 6;
    int lrow = lane & 15, g = lane >> 4;
    int qw = qt * 64 + wid * 16;
    __shared__ f16 Ks[128][72];     // [key][d]
    __shared__ f16 Vt[64][136];     // [d][key]
    __shared__ f16 Ps[4][16][136];  // per-wave P [qrow][key]

    // Q load + fused rope + scale (0.125 * log2e folded in; softmax uses exp2)
    const f16* qrow = q + (size_t)(b * T + qw + lrow) * 1024 + h * 64;
    f16x8 x0 = *(const f16x8*)&qrow[g * 8];
    f16x8 x1 = *(const f16x8*)&qrow[g * 8 + 32];
    const float* cr = cost + (qw + lrow) * 32 + g * 8;
    const float* srp = sint + (qw + lrow) * 32 + g * 8;
    f16x8 qf0, qf1;
    const float qsc = 0.125f * 1.4426950408889634f;
#pragma unroll
    for (int j = 0; j < 8; ++j) {
        float c = cr[j], s = srp[j];
        float a0 = (float)x0[j], a1 = (float)x1[j];
        qf0[j] = (f16)((a0 * c - a1 * s) * qsc);
        qf1[j] = (f16)((a1 * c + a0 * s) * qsc);
    }

    float m[4] = {-1e30f, -1e30f, -1e30f, -1e30f};
    float l[4] = {0.f, 0.f, 0.f, 0.f};
    f32x4 o[4];
#pragma unroll
    for (int dt = 0; dt < 4; ++dt) o[dt] = (f32x4){0.f, 0.f, 0.f, 0.f};

    int kr = tid >> 1, kc = (tid & 1) * 32;   // staging: row kr (0..127), 32 cols
    int ntiles = (qt >> 1) + 1;
    for (int kt = 0; kt < ntiles; ++kt) {
        int k0 = kt * 128;
        const f16* kb = k + (size_t)(b * T + k0 + kr) * 64 + kc;
        const f16* vb = v + (size_t)(b * T + k0 + kr) * 64 + kc;
        f16x8 kv0 = ((const f16x8*)kb)[0], kv1 = ((const f16x8*)kb)[1];
        f16x8 kv2 = ((const f16x8*)kb)[2], kv3 = ((const f16x8*)kb)[3];
        *(f16x8*)&Ks[kr][kc]      = kv0;
        *(f16x8*)&Ks[kr][kc + 8]  = kv1;
        *(f16x8*)&Ks[kr][kc + 16] = kv2;
        *(f16x8*)&Ks[kr][kc + 24] = kv3;
        f16x8 vv0 = ((const f16x8*)vb)[0], vv1 = ((const f16x8*)vb)[1];
        f16x8 vv2 = ((const f16x8*)vb)[2], vv3 = ((const f16x8*)vb)[3];
#pragma unroll
        for (int j = 0; j < 8; ++j) {
            Vt[kc + j][kr]      = vv0[j];
            Vt[kc + 8 + j][kr]  = vv1[j];
            Vt[kc + 16 + j][kr] = vv2[j];
            Vt[kc + 24 + j][kr] = vv3[j];
        }
        __syncthreads();

        // S = Q K^T over 8 key sub-tiles
        f32x4 s[8];
#pragma unroll
        for (int t = 0; t < 8; ++t) {
            f16x8 kf0 = *(const f16x8*)&Ks[t * 16 + lrow][g * 8];
            f16x8 kf1 = *(const f16x8*)&Ks[t * 16 + lrow][32 + g * 8];
            f32x4 z = (f32x4){0.f, 0.f, 0.f, 0.f};
            z = MFMA16(qf0, kf0, z);
            z = MFMA16(qf1, kf1, z);
            s[t] = z;
        }
        // online softmax; lane: rows g*4+rr, key cols t*16+lrow
        bool lastt = (kt == ntiles - 1);
#pragma unroll
        for (int rr = 0; rr < 4; ++rr) {
            int qab = qw + g * 4 + rr;
            if (lastt) {
#pragma unroll
                for (int t = 0; t < 8; ++t) {
                    int kab = k0 + t * 16 + lrow;
                    if (kab > qab) s[t][rr] = -1e30f;
                }
            }
            float mx = s[0][rr];
#pragma unroll
            for (int t = 1; t < 8; ++t) mx = fmaxf(mx, s[t][rr]);
#pragma unroll
            for (int off = 1; off < 16; off <<= 1) mx = fmaxf(mx, __shfl_xor(mx, off));
            float mn = fmaxf(m[rr], mx);
            float alpha = exp2f(m[rr] - mn);
            float rs = 0.f;
#pragma unroll
            for (int t = 0; t < 8; ++t) {
                float p = exp2f(s[t][rr] - mn);
                s[t][rr] = p;
                rs += p;
            }
#pragma unroll
            for (int off = 1; off < 16; off <<= 1) rs += __shfl_xor(rs, off);
            l[rr] = l[rr] * alpha + rs;
            m[rr] = mn;
#pragma unroll
            for (int dt = 0; dt < 4; ++dt) o[dt][rr] *= alpha;
        }
        // P -> per-wave LDS (same-wave roundtrip; no barrier needed)
#pragma unroll
        for (int t = 0; t < 8; ++t)
#pragma unroll
            for (int rr = 0; rr < 4; ++rr)
                Ps[wid][g * 4 + rr][t * 16 + lrow] = (f16)s[t][rr];
        // PV: 4 key-chunks of 32
#pragma unroll
        for (int ch = 0; ch < 4; ++ch) {
            f16x8 pf = *(const f16x8*)&Ps[wid][lrow][ch * 32 + g * 8];
#pragma unroll
            for (int dt = 0; dt < 4; ++dt) {
                f16x8 vf = *(const f16x8*)&Vt[dt * 16 + lrow][ch * 32 + g * 8];
                o[dt] = MFMA16(pf, vf, o[dt]);
            }
        }
        __syncthreads();
    }
    // epilogue
#pragma unroll
    for (int rr = 0; rr < 4; ++rr) {
        float inv = 1.f / l[rr];
        int qab = qw + g * 4 + rr;
#pragma unroll
        for (int dt = 0; dt < 4; ++dt)
            ao[(size_t)(b * T + qab) * 1024 + h * 64 + dt * 16 + lrow] = (f16)(o[dt][rr] * inv);
    }
}

extern "C" void kernel_launch(void* const* d_in, const int* in_sizes, int n_in,
                              void* d_out, int out_size, void* d_ws, size_t ws_size,
                              hipStream_t stream)
{
    (void)in_sizes; (void)n_in; (void)out_size; (void)ws_size;
    const float* x  = (const float*)d_in[0];
    const float* Wq = (const float*)d_in[1];
    const float* Wk = (const float*)d_in[2];
    const float* Wv = (const float*)d_in[3];
    const float* Wo = (const float*)d_in[4];
    float* out = (float*)d_out;

    char* w = (char*)d_ws;
    size_t off = 0;
    auto alloc = [&](size_t bytes) -> void* {
        void* p = (void*)(w + off);
        off += (bytes + 255) & ~(size_t)255;
        return p;
    };
    f16* xb   = (f16*)alloc(4194304ull * 2);   // x f16 [4096,1024]
    f16* Wqb  = (f16*)alloc(1048576ull * 2);
    f16* Wkvb = (f16*)alloc(131072ull * 2);    // [1024,128] = Wk|Wv
    f16* Wob  = (f16*)alloc(1048576ull * 2);
    f16* qg   = (f16*)alloc(4194304ull * 2);   // q proj [4096,1024] (un-roped; rope fused in attn)
    f16* krp  = (f16*)alloc(262144ull * 2);    // rope'd k [4096,64]
    f16* vg   = (f16*)alloc(262144ull * 2);    // v [4096,64]
    f16* ao   = (f16*)alloc(4194304ull * 2);   // attn out [4096,1024]
    float* cost = (float*)alloc(65536ull * 4);
    float* sint = (float*)alloc(65536ull * 4);

    cvt_kernel<<<4096, 256, 0, stream>>>(x,  xb,  1048576);
    cvt_kernel<<<1024, 256, 0, stream>>>(Wq, Wqb, 262144);
    cvt_kv_kernel<<<128, 256, 0, stream>>>(Wk, Wv, Wkvb);
    cvt_kernel<<<1024, 256, 0, stream>>>(Wo, Wob, 262144);
    tables_kernel<<<256, 256, 0, stream>>>(cost, sint);

    gemm_f16<128, 0><<<dim3(8, 32), 256, 0, stream>>>(xb, Wqb, qg, nullptr, nullptr, nullptr, nullptr, 4096, 1024, 1024);
    gemm_f16<128, 2><<<dim3(1, 32), 256, 0, stream>>>(xb, Wkvb, nullptr, krp, vg, cost, sint, 4096, 128, 1024);

    attn_kernel<<<dim3(32, 32), 256, 0, stream>>>(qg, krp, vg, ao, cost, sint);

    gemm_f16<128, 1><<<dim3(8, 32), 256, 0, stream>>>(ao, Wob, out, nullptr, nullptr, nullptr, nullptr, 4096, 1024, 1024);
}

// Round 3
// 278.574 us; speedup vs baseline: 1.2024x; 1.0993x over previous
//
#include <hip/hip_runtime.h>
#include <hip/hip_bf16.h>

typedef _Float16 f16;
typedef __attribute__((ext_vector_type(8))) _Float16 f16x8;
typedef __attribute__((ext_vector_type(4))) _Float16 f16x4;
typedef __attribute__((ext_vector_type(4))) float f32x4;

#define MFMA16(a, b, c) __builtin_amdgcn_mfma_f32_16x16x32_f16(a, b, c, 0, 0, 0)

// ---------------- fp32 -> f16 convert (vectorized) ----------------
__global__ __launch_bounds__(256) void cvt_kernel(const float* __restrict__ in, f16* __restrict__ out, int n4)
{
    int i = blockIdx.x * 256 + threadIdx.x;
    if (i >= n4) return;
    float4 v = ((const float4*)in)[i];
    f16x4 o;
    o[0] = (f16)v.x; o[1] = (f16)v.y; o[2] = (f16)v.z; o[3] = (f16)v.w;
    *(f16x4*)(out + 4 * (size_t)i) = o;
}

// ---------------- Wk|Wv fused convert -> [1024][128] ----------------
__global__ __launch_bounds__(256) void cvt_kv_kernel(const float* __restrict__ Wk, const float* __restrict__ Wv,
                                                     f16* __restrict__ out)
{
    int i = blockIdx.x * 256 + threadIdx.x;   // f32x4 index over [1024][128]
    if (i >= 32768) return;
    int col = (i & 31) * 4;
    int row = i >> 5;
    float4 v = (col < 64) ? ((const float4*)(Wk + (size_t)row * 64 + col))[0]
                          : ((const float4*)(Wv + (size_t)row * 64 + col - 64))[0];
    f16x4 o;
    o[0] = (f16)v.x; o[1] = (f16)v.y; o[2] = (f16)v.z; o[3] = (f16)v.w;
    *(f16x4*)(out + 4 * (size_t)i) = o;
}

// ---------------- RoPE tables (f32) ----------------
__global__ __launch_bounds__(256) void tables_kernel(float* __restrict__ cost, float* __restrict__ sint)
{
    int idx = blockIdx.x * 256 + threadIdx.x;
    if (idx >= 2048 * 32) return;
    int t = idx >> 5, i = idx & 31;
    // inv_freq = 10000^(-2i/64) = exp2(-(2i/64)*log2(10000))
    float invf = exp2f(-(float)(2 * i) * (13.287712379549449f / 64.0f));
    float a = (float)t * invf;
    cost[idx] = cosf(a);
    sint[idx] = sinf(a);
}

// ---------------- f16 GEMM: C[M,N] = A[M,K] @ B[K,N] ----------------
// BM=128 fixed, 256 threads = 4 waves in 2x2, wave tile 64 x BN/2, BK=32.
// MODE 0: f16 C out. MODE 1: f32 C out. MODE 2: N=128 KV mode -> rope'd K to kout[.,64], V to vout[.,64].
template<int BN, int MODE>
__global__ __launch_bounds__(256) void gemm_f16(const f16* __restrict__ A, const f16* __restrict__ B,
                                                void* __restrict__ Cv, f16* __restrict__ kout, f16* __restrict__ vout,
                                                const float* __restrict__ cost, const float* __restrict__ sint,
                                                int M, int N, int K)
{
    constexpr int BM = 128, BK = 32, LDP = BK + 8;
    constexpr int FM = 4, FN = BN / 32;
    __shared__ f16 As[BM][LDP];
    __shared__ f16 Bs[BN][LDP];   // stored transposed: Bs[n][k]
    int tid = threadIdx.x, lane = tid & 63, wid = tid >> 6;
    int wr = wid >> 1, wc = wid & 1;
    int row0 = blockIdx.y * BM, col0 = blockIdx.x * BN;
    int lrow = lane & 15, lk = (lane >> 4) * 8;
    f32x4 acc[FM][FN];
#pragma unroll
    for (int a = 0; a < FM; ++a)
#pragma unroll
        for (int bb = 0; bb < FN; ++bb) acc[a][bb] = (f32x4){0.f, 0.f, 0.f, 0.f};

    int ar = tid >> 2, ac = (tid & 3) * 8;
    constexpr int TPR = BN / 8;
    int kr = tid / TPR, c8 = (tid % TPR) * 8;

    for (int k0 = 0; k0 < K; k0 += BK) {
        f16x8 av0 = *(const f16x8*)&A[(size_t)(row0 + ar) * K + k0 + ac];
        f16x8 av1 = *(const f16x8*)&A[(size_t)(row0 + ar + 64) * K + k0 + ac];
        *(f16x8*)&As[ar][ac] = av0;
        *(f16x8*)&As[ar + 64][ac] = av1;
#pragma unroll
        for (int kk = kr; kk < BK; kk += 256 / TPR) {
            f16x8 bv = *(const f16x8*)&B[(size_t)(k0 + kk) * N + col0 + c8];
#pragma unroll
            for (int j = 0; j < 8; ++j) Bs[c8 + j][kk] = bv[j];
        }
        __syncthreads();
        f16x8 af[FM], bfr[FN];
#pragma unroll
        for (int fm = 0; fm < FM; ++fm) af[fm] = *(const f16x8*)&As[wr * 64 + fm * 16 + lrow][lk];
#pragma unroll
        for (int fn = 0; fn < FN; ++fn) bfr[fn] = *(const f16x8*)&Bs[wc * (BN / 2) + fn * 16 + lrow][lk];
#pragma unroll
        for (int fm = 0; fm < FM; ++fm)
#pragma unroll
            for (int fn = 0; fn < FN; ++fn)
                acc[fm][fn] = MFMA16(af[fm], bfr[fn], acc[fm][fn]);
        __syncthreads();
    }
    // epilogue: C/D layout col=lane&15, row=(lane>>4)*4+reg
    if constexpr (MODE == 2) {
        // wc==0 waves own cols 0..63 = K head (rope); wc==1 own cols 64..127 = V head
#pragma unroll
        for (int fm = 0; fm < FM; ++fm)
#pragma unroll
            for (int r = 0; r < 4; ++r) {
                int row = row0 + wr * 64 + fm * 16 + (lane >> 4) * 4 + r;
                int t = row & 2047;
                if (wc == 0) {
#pragma unroll
                    for (int fn = 0; fn < 2; ++fn) {
                        int i = fn * 16 + lrow;
                        float c = cost[t * 32 + i], s = sint[t * 32 + i];
                        float x0 = acc[fm][fn][r], x1 = acc[fm][fn + 2][r];
                        kout[(size_t)row * 64 + i]      = (f16)(x0 * c - x1 * s);
                        kout[(size_t)row * 64 + i + 32] = (f16)(x1 * c + x0 * s);
                    }
                } else {
#pragma unroll
                    for (int fn = 0; fn < FN; ++fn)
                        vout[(size_t)row * 64 + fn * 16 + lrow] = (f16)acc[fm][fn][r];
                }
            }
    } else {
#pragma unroll
        for (int fm = 0; fm < FM; ++fm)
#pragma unroll
            for (int fn = 0; fn < FN; ++fn)
#pragma unroll
                for (int r = 0; r < 4; ++r) {
                    int row = row0 + wr * 64 + fm * 16 + (lane >> 4) * 4 + r;
                    int col = col0 + wc * (BN / 2) + fn * 16 + lrow;
                    if (MODE == 1) ((float*)Cv)[(size_t)row * N + col] = acc[fm][fn][r];
                    else           ((f16*)Cv)[(size_t)row * N + col] = (f16)acc[fm][fn][r];
                }
    }
}

// ---------------- causal MQA flash attention, key-split flash-decoding ----------------
// q: [B*T, 1024] (raw proj, h-major), k: [B*T,64] rope'd, v: [B*T,64]
// ao: [B*T,1024]; partial: per-slot {f16 o[64][64]; f32 m[64]; f32 l[64]} = 8704B
// grid (48, 32): chunk c -> (qt, ch): c<32 -> qt=31-(c>>1) (2 chunks of <=16 key-tiles),
// c>=32 -> qt=47-c (single chunk). Block 256 = 4 waves, wave owns 16 q rows, KVBLK=64.
__global__ __launch_bounds__(256, 4) void attn_kernel(const f16* __restrict__ q, const f16* __restrict__ k,
                                                      const f16* __restrict__ v, f16* __restrict__ ao,
                                                      const float* __restrict__ cost, const float* __restrict__ sint,
                                                      char* __restrict__ partial)
{
    constexpr int T = 2048;
    int c = blockIdx.x, bh = blockIdx.y;
    int b = bh >> 4, h = bh & 15;
    int qt, ch, nch;
    if (c < 32) { qt = 31 - (c >> 1); ch = c & 1; nch = 2; }
    else        { qt = 47 - c; ch = 0; nch = 1; }
    int ntiles = qt + 1;                       // 64-key tiles
    int tbeg = ch * 16;
    int tend = (nch == 2 && ch == 0) ? 16 : ntiles;

    int tid = threadIdx.x, lane = tid & 63, wid = tid >> 6;
    int lrow = lane & 15, g = lane >> 4;
    int qw = qt * 64 + wid * 16;
    __shared__ f16 Ks[64][72];     // [key][d]
    __shared__ f16 Vt[64][72];     // [d][key]
    __shared__ f16 Ps[4][16][72];  // per-wave P [qrow][key]

    // Q load + fused rope + scale (0.125 * log2e folded; softmax in exp2 space)
    const f16* qrow = q + (size_t)(b * T + qw + lrow) * 1024 + h * 64;
    f16x8 x0 = *(const f16x8*)&qrow[g * 8];
    f16x8 x1 = *(const f16x8*)&qrow[g * 8 + 32];
    const float* cr  = cost + (qw + lrow) * 32 + g * 8;
    const float* srp = sint + (qw + lrow) * 32 + g * 8;
    f16x8 qf0, qf1;
    const float qsc = 0.125f * 1.4426950408889634f;
#pragma unroll
    for (int j = 0; j < 8; ++j) {
        float cc = cr[j], ss = srp[j];
        float a0 = (float)x0[j], a1 = (float)x1[j];
        qf0[j] = (f16)((a0 * cc - a1 * ss) * qsc);
        qf1[j] = (f16)((a1 * cc + a0 * ss) * qsc);
    }

    float m[4] = {-1e30f, -1e30f, -1e30f, -1e30f};
    float l[4] = {0.f, 0.f, 0.f, 0.f};   // lane-partial row sums (deferred reduce)
    f32x4 o[4];
#pragma unroll
    for (int dt = 0; dt < 4; ++dt) o[dt] = (f32x4){0.f, 0.f, 0.f, 0.f};

    int skr = wid * 16 + (lane >> 2);   // K staging row (per-wave row range)
    int skc = (lane & 3) * 16;          // K staging col (2 x f16x8)
    const f16* kbase = k + (size_t)b * T * 64;
    const f16* vbase = v + (size_t)b * T * 64;

    for (int t = tbeg; t < tend; ++t) {
        int k0 = t * 64;
        // stage K [key][d]: coalesced rows
        const f16* kb = kbase + (size_t)(k0 + skr) * 64 + skc;
        *(f16x8*)&Ks[skr][skc]     = ((const f16x8*)kb)[0];
        *(f16x8*)&Ks[skr][skc + 8] = ((const f16x8*)kb)[1];
        // stage V transposed [d][key]: wave wid owns d-chunk [wid*16,+16), lane owns key row `lane`
        const f16* vb = vbase + (size_t)(k0 + lane) * 64 + wid * 16;
        f16x8 vv0 = ((const f16x8*)vb)[0];
        f16x8 vv1 = ((const f16x8*)vb)[1];
#pragma unroll
        for (int j = 0; j < 8; ++j) {
            Vt[wid * 16 + j][lane]     = vv0[j];   // row-contiguous writes: conflict-free
            Vt[wid * 16 + 8 + j][lane] = vv1[j];
        }
        __syncthreads();

        // S = Q K^T over 4 key sub-tiles
        f32x4 s[4];
#pragma unroll
        for (int tt = 0; tt < 4; ++tt) {
            f16x8 kf0 = *(const f16x8*)&Ks[tt * 16 + lrow][g * 8];
            f16x8 kf1 = *(const f16x8*)&Ks[tt * 16 + lrow][32 + g * 8];
            f32x4 z = (f32x4){0.f, 0.f, 0.f, 0.f};
            z = MFMA16(qf0, kf0, z);
            z = MFMA16(qf1, kf1, z);
            s[tt] = z;
        }
        bool lastt = (t == ntiles - 1);
#pragma unroll
        for (int rr = 0; rr < 4; ++rr) {
            int qab = qw + g * 4 + rr;
            if (lastt) {
#pragma unroll
                for (int tt = 0; tt < 4; ++tt)
                    if (k0 + tt * 16 + lrow > qab) s[tt][rr] = -1e30f;
            }
            float mx = fmaxf(fmaxf(s[0][rr], s[1][rr]), fmaxf(s[2][rr], s[3][rr]));
#pragma unroll
            for (int off = 1; off < 16; off <<= 1) mx = fmaxf(mx, __shfl_xor(mx, off));
            float mn = fmaxf(m[rr], mx);
            float alpha = exp2f(m[rr] - mn);
            m[rr] = mn;
            float p0 = exp2f(s[0][rr] - mn), p1 = exp2f(s[1][rr] - mn);
            float p2 = exp2f(s[2][rr] - mn), p3 = exp2f(s[3][rr] - mn);
            s[0][rr] = p0; s[1][rr] = p1; s[2][rr] = p2; s[3][rr] = p3;
            l[rr] = l[rr] * alpha + ((p0 + p1) + (p2 + p3));
#pragma unroll
            for (int dt = 0; dt < 4; ++dt) o[dt][rr] *= alpha;
        }
        // P -> per-wave LDS (same-wave roundtrip; no barrier)
#pragma unroll
        for (int tt = 0; tt < 4; ++tt)
#pragma unroll
            for (int rr = 0; rr < 4; ++rr)
                Ps[wid][g * 4 + rr][tt * 16 + lrow] = (f16)s[tt][rr];
        // PV: 2 key-chunks of 32
#pragma unroll
        for (int chk = 0; chk < 2; ++chk) {
            f16x8 pf = *(const f16x8*)&Ps[wid][lrow][chk * 32 + g * 8];
#pragma unroll
            for (int dt = 0; dt < 4; ++dt) {
                f16x8 vf = *(const f16x8*)&Vt[dt * 16 + lrow][chk * 32 + g * 8];
                o[dt] = MFMA16(pf, vf, o[dt]);
            }
        }
        __syncthreads();
    }
    // final row-sum reduce of lane-partial l
#pragma unroll
    for (int rr = 0; rr < 4; ++rr)
#pragma unroll
        for (int off = 1; off < 16; off <<= 1) l[rr] += __shfl_xor(l[rr], off);

    if (nch == 1) {
#pragma unroll
        for (int rr = 0; rr < 4; ++rr) {
            float inv = 1.f / l[rr];
            int qab = qw + g * 4 + rr;
#pragma unroll
            for (int dt = 0; dt < 4; ++dt)
                ao[(size_t)(b * T + qab) * 1024 + h * 64 + dt * 16 + lrow] = (f16)(o[dt][rr] * inv);
        }
    } else {
        char* slot = partial + ((size_t)(bh * 16 + (qt - 16)) * 2 + ch) * 8704;
        f16* op = (f16*)slot;
        float* mp = (float*)(slot + 8192);
        float* lp = mp + 64;
#pragma unroll
        for (int rr = 0; rr < 4; ++rr) {
            int row = wid * 16 + g * 4 + rr;
#pragma unroll
            for (int dt = 0; dt < 4; ++dt)
                op[row * 64 + dt * 16 + lrow] = (f16)o[dt][rr];
            if (lrow == 0) { mp[row] = m[rr]; lp[row] = l[rr]; }
        }
    }
}

// ---------------- combine partials (2 chunks) for qt>=16 ----------------
__global__ __launch_bounds__(256) void combine_kernel(const char* __restrict__ partial, f16* __restrict__ ao)
{
    constexpr int T = 2048;
    int qt = 16 + blockIdx.x, bh = blockIdx.y;
    int b = bh >> 4, h = bh & 15;
    int tid = threadIdx.x;
    int row = tid >> 2, dp = (tid & 3) * 16;
    const char* s0 = partial + ((size_t)(bh * 16 + (qt - 16)) * 2) * 8704;
    const char* s1 = s0 + 8704;
    const f16* o0 = (const f16*)s0; const float* m0 = (const float*)(s0 + 8192); const float* l0 = m0 + 64;
    const f16* o1 = (const f16*)s1; const float* m1 = (const float*)(s1 + 8192); const float* l1 = m1 + 64;
    float mm0 = m0[row], mm1 = m1[row];
    float M = fmaxf(mm0, mm1);
    float a0 = exp2f(mm0 - M), a1 = exp2f(mm1 - M);
    float inv = 1.f / (l0[row] * a0 + l1[row] * a1);
    f16x8 u0 = ((const f16x8*)(o0 + row * 64 + dp))[0];
    f16x8 u1 = ((const f16x8*)(o0 + row * 64 + dp))[1];
    f16x8 w0 = ((const f16x8*)(o1 + row * 64 + dp))[0];
    f16x8 w1 = ((const f16x8*)(o1 + row * 64 + dp))[1];
    f16x8 r0, r1;
#pragma unroll
    for (int j = 0; j < 8; ++j) {
        r0[j] = (f16)(((float)u0[j] * a0 + (float)w0[j] * a1) * inv);
        r1[j] = (f16)(((float)u1[j] * a0 + (float)w1[j] * a1) * inv);
    }
    f16* dst = ao + (size_t)(b * T + qt * 64 + row) * 1024 + h * 64 + dp;
    *(f16x8*)dst = r0;
    *(f16x8*)(dst + 8) = r1;
}

extern "C" void kernel_launch(void* const* d_in, const int* in_sizes, int n_in,
                              void* d_out, int out_size, void* d_ws, size_t ws_size,
                              hipStream_t stream)
{
    (void)in_sizes; (void)n_in; (void)out_size; (void)ws_size;
    const float* x  = (const float*)d_in[0];
    const float* Wq = (const float*)d_in[1];
    const float* Wk = (const float*)d_in[2];
    const float* Wv = (const float*)d_in[3];
    const float* Wo = (const float*)d_in[4];
    float* out = (float*)d_out;

    char* w = (char*)d_ws;
    size_t off = 0;
    auto alloc = [&](size_t bytes) -> void* {
        void* p = (void*)(w + off);
        off += (bytes + 255) & ~(size_t)255;
        return p;
    };
    f16* xb   = (f16*)alloc(4194304ull * 2);   // x f16 [4096,1024]  (reused as attn partial buffer)
    f16* Wqb  = (f16*)alloc(1048576ull * 2);   // (also part of partial region; dead after Q-GEMM)
    f16* Wkvb = (f16*)alloc(131072ull * 2);    // [1024,128] = Wk|Wv
    f16* Wob  = (f16*)alloc(1048576ull * 2);
    f16* qg   = (f16*)alloc(4194304ull * 2);   // q proj [4096,1024] (rope fused in attn)
    f16* krp  = (f16*)alloc(262144ull * 2);    // rope'd k [4096,64]
    f16* vg   = (f16*)alloc(262144ull * 2);    // v [4096,64]
    f16* ao   = (f16*)alloc(4194304ull * 2);   // attn out [4096,1024]
    float* cost = (float*)alloc(65536ull * 4);
    float* sint = (float*)alloc(65536ull * 4);
    // partial buffer: 1024 slots x 8704B = 8.91MB, aliases xb+Wqb (dead after GEMMs)
    char* partial = (char*)xb;

    cvt_kernel<<<4096, 256, 0, stream>>>(x,  xb,  1048576);
    cvt_kernel<<<1024, 256, 0, stream>>>(Wq, Wqb, 262144);
    cvt_kv_kernel<<<128, 256, 0, stream>>>(Wk, Wv, Wkvb);
    cvt_kernel<<<1024, 256, 0, stream>>>(Wo, Wob, 262144);
    tables_kernel<<<256, 256, 0, stream>>>(cost, sint);

    gemm_f16<128, 0><<<dim3(8, 32), 256, 0, stream>>>(xb, Wqb, qg, nullptr, nullptr, nullptr, nullptr, 4096, 1024, 1024);
    gemm_f16<128, 2><<<dim3(1, 32), 256, 0, stream>>>(xb, Wkvb, nullptr, krp, vg, cost, sint, 4096, 128, 1024);

    attn_kernel<<<dim3(48, 32), 256, 0, stream>>>(qg, krp, vg, ao, cost, sint, partial);
    combine_kernel<<<dim3(16, 32), 256, 0, stream>>>(partial, ao);

    gemm_f16<128, 1><<<dim3(8, 32), 256, 0, stream>>>(ao, Wob, out, nullptr, nullptr, nullptr, nullptr, 4096, 1024, 1024);
}

// Round 4
// 213.337 us; speedup vs baseline: 1.5700x; 1.3058x over previous
//
#include <hip/hip_runtime.h>
#include <hip/hip_bf16.h>

typedef _Float16 f16;
typedef __attribute__((ext_vector_type(8))) _Float16 f16x8;
typedef __attribute__((ext_vector_type(4))) _Float16 f16x4;
typedef __attribute__((ext_vector_type(4))) float f32x4;

#define MFMA16(a, b, c) __builtin_amdgcn_mfma_f32_16x16x32_f16(a, b, c, 0, 0, 0)

// ---------------- merged fp32 -> f16 convert for all inputs ----------------
// ranges in f32x4 units: [0,1048576) x->xb ; [1048576,1310720) Wq->Wall[:,0:1024]
// [1310720,1343488) Wk|Wv->Wall[:,1024:1152] ; [1343488,1605632) Wo->Wob
__global__ __launch_bounds__(256) void cvt_all_kernel(const float* __restrict__ x, const float* __restrict__ Wq,
                                                      const float* __restrict__ Wk, const float* __restrict__ Wv,
                                                      const float* __restrict__ Wo, f16* __restrict__ xb,
                                                      f16* __restrict__ Wall, f16* __restrict__ Wob)
{
    int i = blockIdx.x * 256 + threadIdx.x;
    float4 v;
    f16* dst;
    if (i < 1048576) {
        v = ((const float4*)x)[i];
        dst = xb + 4 * (size_t)i;
    } else if (i < 1310720) {
        int j = i - 1048576;
        v = ((const float4*)Wq)[j];
        int row = j >> 8, col = (j & 255) * 4;
        dst = Wall + (size_t)row * 1152 + col;
    } else if (i < 1343488) {
        int j = i - 1310720;
        int row = j >> 5, col = (j & 31) * 4;
        v = (col < 64) ? ((const float4*)(Wk + (size_t)row * 64 + col))[0]
                       : ((const float4*)(Wv + (size_t)row * 64 + col - 64))[0];
        dst = Wall + (size_t)row * 1152 + 1024 + col;
    } else {
        int j = i - 1343488;
        v = ((const float4*)Wo)[j];
        dst = Wob + 4 * (size_t)j;
    }
    f16x4 o;
    o[0] = (f16)v.x; o[1] = (f16)v.y; o[2] = (f16)v.z; o[3] = (f16)v.w;
    *(f16x4*)dst = o;
}

// ---------------- f16 GEMM: C[M,N] = A[M,K] @ B[K,N] ----------------
// BM=128, BN=128, 256 threads = 4 waves 2x2, BK=32.
// MODE 1: f32 C out (stride Nc). MODE 2: qkv — bx<8: f16 C (stride Nc); bx==8: rope'd K + V heads.
template<int MODE>
__global__ __launch_bounds__(256) void gemm_f16(const f16* __restrict__ A, const f16* __restrict__ B,
                                                void* __restrict__ Cv, f16* __restrict__ kout, f16* __restrict__ vout,
                                                int M, int Nb, int Nc, int K)
{
    constexpr int BM = 128, BN = 128, BK = 32, LDP = BK + 8;
    constexpr int FM = 4, FN = 4;
    __shared__ f16 As[BM][LDP];
    __shared__ f16 Bs[BN][LDP];   // transposed: Bs[n][k]
    int tid = threadIdx.x, lane = tid & 63, wid = tid >> 6;
    int wr = wid >> 1, wc = wid & 1;
    int row0 = blockIdx.y * BM, col0 = blockIdx.x * BN;
    int lrow = lane & 15, lk = (lane >> 4) * 8;
    f32x4 acc[FM][FN];
#pragma unroll
    for (int a = 0; a < FM; ++a)
#pragma unroll
        for (int bb = 0; bb < FN; ++bb) acc[a][bb] = (f32x4){0.f, 0.f, 0.f, 0.f};

    int ar = tid >> 2, ac = (tid & 3) * 8;
    int kr = tid / 16, c8 = (tid % 16) * 8;

    for (int k0 = 0; k0 < K; k0 += BK) {
        f16x8 av0 = *(const f16x8*)&A[(size_t)(row0 + ar) * K + k0 + ac];
        f16x8 av1 = *(const f16x8*)&A[(size_t)(row0 + ar + 64) * K + k0 + ac];
        *(f16x8*)&As[ar][ac] = av0;
        *(f16x8*)&As[ar + 64][ac] = av1;
#pragma unroll
        for (int kk = kr; kk < BK; kk += 16) {
            f16x8 bv = *(const f16x8*)&B[(size_t)(k0 + kk) * Nb + col0 + c8];
#pragma unroll
            for (int j = 0; j < 8; ++j) Bs[c8 + j][kk] = bv[j];
        }
        __syncthreads();
        f16x8 af[FM], bfr[FN];
#pragma unroll
        for (int fm = 0; fm < FM; ++fm) af[fm] = *(const f16x8*)&As[wr * 64 + fm * 16 + lrow][lk];
#pragma unroll
        for (int fn = 0; fn < FN; ++fn) bfr[fn] = *(const f16x8*)&Bs[wc * 64 + fn * 16 + lrow][lk];
#pragma unroll
        for (int fm = 0; fm < FM; ++fm)
#pragma unroll
            for (int fn = 0; fn < FN; ++fn)
                acc[fm][fn] = MFMA16(af[fm], bfr[fn], acc[fm][fn]);
        __syncthreads();
    }
    // epilogue: C/D layout col=lane&15, row=(lane>>4)*4+reg
    if constexpr (MODE == 2) {
        if (col0 < 1024) {
            f16* C = (f16*)Cv;
#pragma unroll
            for (int fm = 0; fm < FM; ++fm)
#pragma unroll
                for (int fn = 0; fn < FN; ++fn)
#pragma unroll
                    for (int r = 0; r < 4; ++r) {
                        int row = row0 + wr * 64 + fm * 16 + (lane >> 4) * 4 + r;
                        int col = col0 + wc * 64 + fn * 16 + lrow;
                        C[(size_t)row * Nc + col] = (f16)acc[fm][fn][r];
                    }
        } else {
            const float L2B = 13.287712379549449f / 64.0f;
            if (wc == 0) {
                float invf0 = exp2f(-(float)(2 * lrow) * L2B);
                float invf1 = exp2f(-(float)(2 * (16 + lrow)) * L2B);
#pragma unroll
                for (int fm = 0; fm < FM; ++fm)
#pragma unroll
                    for (int r = 0; r < 4; ++r) {
                        int row = row0 + wr * 64 + fm * 16 + (lane >> 4) * 4 + r;
                        float t = (float)(row & 2047);
                        float s0, c0, s1, c1;
                        sincosf(t * invf0, &s0, &c0);
                        sincosf(t * invf1, &s1, &c1);
                        float xa = acc[fm][0][r], xb_ = acc[fm][2][r];
                        kout[(size_t)row * 64 + lrow]      = (f16)(xa * c0 - xb_ * s0);
                        kout[(size_t)row * 64 + lrow + 32] = (f16)(xb_ * c0 + xa * s0);
                        float ya = acc[fm][1][r], yb = acc[fm][3][r];
                        kout[(size_t)row * 64 + 16 + lrow] = (f16)(ya * c1 - yb * s1);
                        kout[(size_t)row * 64 + 48 + lrow] = (f16)(yb * c1 + ya * s1);
                    }
            } else {
#pragma unroll
                for (int fm = 0; fm < FM; ++fm)
#pragma unroll
                    for (int fn = 0; fn < FN; ++fn)
#pragma unroll
                        for (int r = 0; r < 4; ++r) {
                            int row = row0 + wr * 64 + fm * 16 + (lane >> 4) * 4 + r;
                            vout[(size_t)row * 64 + fn * 16 + lrow] = (f16)acc[fm][fn][r];
                        }
            }
        }
    } else {
        float* C = (float*)Cv;
#pragma unroll
        for (int fm = 0; fm < FM; ++fm)
#pragma unroll
            for (int fn = 0; fn < FN; ++fn)
#pragma unroll
                for (int r = 0; r < 4; ++r) {
                    int row = row0 + wr * 64 + fm * 16 + (lane >> 4) * 4 + r;
                    int col = col0 + wc * 64 + fn * 16 + lrow;
                    C[(size_t)row * Nc + col] = acc[fm][fn][r];
                }
    }
}

// ---------------- causal MQA flash attention ----------------
// Swapped QK^T (P[key][qrow] in-lane softmax), XOR-swizzled LDS, double-buffered K/V, 1 barrier/tile.
// q: [B*T,1024] raw proj (rope fused here); k: [B*T,64] rope'd; v: [B*T,64]
// grid (48,32): c<32 -> qt=31-(c>>1), 2 key-chunks; c>=32 -> qt=47-c single chunk.
__global__ __launch_bounds__(256, 3) void attn_kernel(const f16* __restrict__ q, const f16* __restrict__ k,
                                                      const f16* __restrict__ v, f16* __restrict__ ao,
                                                      char* __restrict__ partial)
{
    constexpr int T = 2048;
    int c = blockIdx.x, bh = blockIdx.y;
    int b = bh >> 4, h = bh & 15;
    int qt, ch, nch;
    if (c < 32) { qt = 31 - (c >> 1); ch = c & 1; nch = 2; }
    else        { qt = 47 - c; ch = 0; nch = 1; }
    int ntiles = qt + 1;
    int tbeg = ch * 16;
    int tend = (nch == 2 && ch == 0) ? 16 : ntiles;

    int tid = threadIdx.x, lane = tid & 63, wid = tid >> 6;
    int lrow = lane & 15, g = lane >> 4;
    int qw = qt * 64 + wid * 16;
    int swl = (lrow & 7) << 3;     // read-side swizzle (all read rows ≡ lrow mod 8)

    __shared__ f16 KsB[2][64 * 64];
    __shared__ f16 VtB[2][64 * 64];
    __shared__ f16 PsB[4][16 * 64];

    // Q load + inline rope + scale (0.125*log2e folded; softmax in exp2 space)
    const f16* qrow = q + (size_t)(b * T + qw + lrow) * 1024 + h * 64;
    f16x8 x0 = *(const f16x8*)&qrow[g * 8];
    f16x8 x1 = *(const f16x8*)&qrow[g * 8 + 32];
    f16x8 qf0, qf1;
    {
        const float qsc = 0.125f * 1.4426950408889634f;
        const float L2B = 13.287712379549449f / 64.0f;
        float t_ = (float)(qw + lrow);
#pragma unroll
        for (int j = 0; j < 8; ++j) {
            int i = g * 8 + j;
            float invf = exp2f(-(float)(2 * i) * L2B);
            float ss, cc;
            sincosf(t_ * invf, &ss, &cc);
            float a0 = (float)x0[j], a1 = (float)x1[j];
            qf0[j] = (f16)((a0 * cc - a1 * ss) * qsc);
            qf1[j] = (f16)((a1 * cc + a0 * ss) * qsc);
        }
    }

    float m = -1e30f, l = 0.f;
    f32x4 o[4];
#pragma unroll
    for (int dt = 0; dt < 4; ++dt) o[dt] = (f32x4){0.f, 0.f, 0.f, 0.f};

    int skr = wid * 16 + (lane >> 2);
    int skc = (lane & 3) * 16;
    int swk = (skr & 7) << 3;
    const f16* kbase = k + (size_t)b * T * 64;
    const f16* vbase = v + (size_t)b * T * 64;

    // prologue: stage tile tbeg -> buf 0
    {
        const f16* kb = kbase + (size_t)(tbeg * 64 + skr) * 64 + skc;
        *(f16x8*)&KsB[0][skr * 64 + (skc ^ swk)]       = ((const f16x8*)kb)[0];
        *(f16x8*)&KsB[0][skr * 64 + ((skc + 8) ^ swk)] = ((const f16x8*)kb)[1];
        const f16* vb = vbase + (size_t)(tbeg * 64 + lane) * 64 + wid * 16;
        f16x8 vv0 = ((const f16x8*)vb)[0];
        f16x8 vv1 = ((const f16x8*)vb)[1];
#pragma unroll
        for (int j = 0; j < 8; ++j) {
            VtB[0][(wid * 16 + j) * 64 + (lane ^ (j << 3))]     = vv0[j];
            VtB[0][(wid * 16 + 8 + j) * 64 + (lane ^ (j << 3))] = vv1[j];
        }
    }
    __syncthreads();

    for (int t = tbeg; t < tend; ++t) {
        int cur = (t - tbeg) & 1;
        bool hasnext = (t + 1 < tend);
        f16x8 kn0, kn1, vn0, vn1;
        if (hasnext) {                       // prefetch next tile into regs (latency hidden by compute)
            const f16* kb = kbase + (size_t)((t + 1) * 64 + skr) * 64 + skc;
            kn0 = ((const f16x8*)kb)[0];
            kn1 = ((const f16x8*)kb)[1];
            const f16* vb = vbase + (size_t)((t + 1) * 64 + lane) * 64 + wid * 16;
            vn0 = ((const f16x8*)vb)[0];
            vn1 = ((const f16x8*)vb)[1];
        }
        const f16* Ks = KsB[cur];
        const f16* Vt = VtB[cur];
        f16* Ps = PsB[wid];

        // S^T = K Q : D[key][qrow]; lane holds keys tt*16+g*4+r for q-row lrow
        f32x4 s[4];
#pragma unroll
        for (int tt = 0; tt < 4; ++tt) {
            f16x8 kf0 = *(const f16x8*)&Ks[(tt * 16 + lrow) * 64 + ((g * 8) ^ swl)];
            f16x8 kf1 = *(const f16x8*)&Ks[(tt * 16 + lrow) * 64 + ((32 + g * 8) ^ swl)];
            f32x4 z = (f32x4){0.f, 0.f, 0.f, 0.f};
            z = MFMA16(kf0, qf0, z);
            z = MFMA16(kf1, qf1, z);
            s[tt] = z;
        }
        if (t == ntiles - 1) {               // causal mask, diagonal tile only
            int qab = qw + lrow;
            int kb0 = t * 64 + g * 4;
#pragma unroll
            for (int tt = 0; tt < 4; ++tt)
#pragma unroll
                for (int r = 0; r < 4; ++r)
                    if (kb0 + tt * 16 + r > qab) s[tt][r] = -1e30f;
        }
        // in-lane max tree + 2 cross-lane ops
        float mx0 = fmaxf(fmaxf(s[0][0], s[0][1]), fmaxf(s[0][2], s[0][3]));
        float mx1 = fmaxf(fmaxf(s[1][0], s[1][1]), fmaxf(s[1][2], s[1][3]));
        float mx2 = fmaxf(fmaxf(s[2][0], s[2][1]), fmaxf(s[2][2], s[2][3]));
        float mx3 = fmaxf(fmaxf(s[3][0], s[3][1]), fmaxf(s[3][2], s[3][3]));
        float mx = fmaxf(fmaxf(mx0, mx1), fmaxf(mx2, mx3));
        mx = fmaxf(mx, __shfl_xor(mx, 16));
        mx = fmaxf(mx, __shfl_xor(mx, 32));
        float mn = fmaxf(m, mx);
        float alpha = exp2f(m - mn);
        m = mn;
        float rs = 0.f;
#pragma unroll
        for (int tt = 0; tt < 4; ++tt) {
            f16x4 pw;
#pragma unroll
            for (int r = 0; r < 4; ++r) {
                float p = exp2f(s[tt][r] - mn);
                s[tt][r] = p;
                pw[r] = (f16)p;
            }
            rs += (s[tt][0] + s[tt][1]) + (s[tt][2] + s[tt][3]);
            *(f16x4*)&Ps[lrow * 64 + ((tt * 16 + g * 4) ^ swl)] = pw;
        }
        l = l * alpha + rs;
        // broadcast alpha to the o-rows this lane owns (rows g*4+rr)
        float av0 = __shfl(alpha, g * 4 + 0);
        float av1 = __shfl(alpha, g * 4 + 1);
        float av2 = __shfl(alpha, g * 4 + 2);
        float av3 = __shfl(alpha, g * 4 + 3);
#pragma unroll
        for (int dt = 0; dt < 4; ++dt) {
            o[dt][0] *= av0; o[dt][1] *= av1; o[dt][2] *= av2; o[dt][3] *= av3;
        }
        // PV (same-wave Ps roundtrip; compiler inserts lgkmcnt)
#pragma unroll
        for (int chk = 0; chk < 2; ++chk) {
            f16x8 pf = *(const f16x8*)&Ps[lrow * 64 + ((chk * 32 + g * 8) ^ swl)];
#pragma unroll
            for (int dt = 0; dt < 4; ++dt) {
                f16x8 vf = *(const f16x8*)&Vt[(dt * 16 + lrow) * 64 + ((chk * 32 + g * 8) ^ swl)];
                o[dt] = MFMA16(pf, vf, o[dt]);
            }
        }
        // stage next tile into other buffer (read by no one until the barrier)
        if (hasnext) {
            int nb = cur ^ 1;
            *(f16x8*)&KsB[nb][skr * 64 + (skc ^ swk)]       = kn0;
            *(f16x8*)&KsB[nb][skr * 64 + ((skc + 8) ^ swk)] = kn1;
#pragma unroll
            for (int j = 0; j < 8; ++j) {
                VtB[nb][(wid * 16 + j) * 64 + (lane ^ (j << 3))]     = vn0[j];
                VtB[nb][(wid * 16 + 8 + j) * 64 + (lane ^ (j << 3))] = vn1[j];
            }
        }
        __syncthreads();
    }
    // finish the deferred row-sum
    l += __shfl_xor(l, 16);
    l += __shfl_xor(l, 32);
    float lv[4];
#pragma unroll
    for (int rr = 0; rr < 4; ++rr) lv[rr] = __shfl(l, g * 4 + rr);

    if (nch == 1) {
#pragma unroll
        for (int rr = 0; rr < 4; ++rr) {
            float inv = 1.f / lv[rr];
            int qab = qw + g * 4 + rr;
#pragma unroll
            for (int dt = 0; dt < 4; ++dt)
                ao[(size_t)(b * T + qab) * 1024 + h * 64 + dt * 16 + lrow] = (f16)(o[dt][rr] * inv);
        }
    } else {
        char* slot = partial + ((size_t)(bh * 16 + (qt - 16)) * 2 + ch) * 8704;
        f16* op = (f16*)slot;
        float* mp = (float*)(slot + 8192);
        float* lp = mp + 64;
#pragma unroll
        for (int rr = 0; rr < 4; ++rr) {
            int row = wid * 16 + g * 4 + rr;
#pragma unroll
            for (int dt = 0; dt < 4; ++dt)
                op[row * 64 + dt * 16 + lrow] = (f16)o[dt][rr];
        }
        if (g == 0) { mp[wid * 16 + lrow] = m; lp[wid * 16 + lrow] = l; }
    }
}

// ---------------- combine partials (2 chunks) for qt>=16 ----------------
__global__ __launch_bounds__(256) void combine_kernel(const char* __restrict__ partial, f16* __restrict__ ao)
{
    constexpr int T = 2048;
    int qt = 16 + blockIdx.x, bh = blockIdx.y;
    int b = bh >> 4, h = bh & 15;
    int tid = threadIdx.x;
    int row = tid >> 2, dp = (tid & 3) * 16;
    const char* s0 = partial + ((size_t)(bh * 16 + (qt - 16)) * 2) * 8704;
    const char* s1 = s0 + 8704;
    const f16* o0 = (const f16*)s0; const float* m0 = (const float*)(s0 + 8192); const float* l0 = m0 + 64;
    const f16* o1 = (const f16*)s1; const float* m1 = (const float*)(s1 + 8192); const float* l1 = m1 + 64;
    float mm0 = m0[row], mm1 = m1[row];
    float M = fmaxf(mm0, mm1);
    float a0 = exp2f(mm0 - M), a1 = exp2f(mm1 - M);
    float inv = 1.f / (l0[row] * a0 + l1[row] * a1);
    f16x8 u0 = ((const f16x8*)(o0 + row * 64 + dp))[0];
    f16x8 u1 = ((const f16x8*)(o0 + row * 64 + dp))[1];
    f16x8 w0 = ((const f16x8*)(o1 + row * 64 + dp))[0];
    f16x8 w1 = ((const f16x8*)(o1 + row * 64 + dp))[1];
    f16x8 r0, r1;
#pragma unroll
    for (int j = 0; j < 8; ++j) {
        r0[j] = (f16)(((float)u0[j] * a0 + (float)w0[j] * a1) * inv);
        r1[j] = (f16)(((float)u1[j] * a0 + (float)w1[j] * a1) * inv);
    }
    f16* dst = ao + (size_t)(b * T + qt * 64 + row) * 1024 + h * 64 + dp;
    *(f16x8*)dst = r0;
    *(f16x8*)(dst + 8) = r1;
}

extern "C" void kernel_launch(void* const* d_in, const int* in_sizes, int n_in,
                              void* d_out, int out_size, void* d_ws, size_t ws_size,
                              hipStream_t stream)
{
    (void)in_sizes; (void)n_in; (void)out_size; (void)ws_size;
    const float* x  = (const float*)d_in[0];
    const float* Wq = (const float*)d_in[1];
    const float* Wk = (const float*)d_in[2];
    const float* Wv = (const float*)d_in[3];
    const float* Wo = (const float*)d_in[4];
    float* out = (float*)d_out;

    char* w = (char*)d_ws;
    size_t off = 0;
    auto alloc = [&](size_t bytes) -> void* {
        void* p = (void*)(w + off);
        off += (bytes + 255) & ~(size_t)255;
        return p;
    };
    f16* xb   = (f16*)alloc(4194304ull * 2);     // x f16 [4096,1024] (reused as attn partial buffer)
    f16* Wall = (f16*)alloc(1179648ull * 2);     // [1024,1152] = Wq|Wk|Wv (also partial overflow region)
    f16* Wob  = (f16*)alloc(1048576ull * 2);
    f16* qg   = (f16*)alloc(4194304ull * 2);     // q proj [4096,1024] (rope fused in attn)
    f16* krp  = (f16*)alloc(262144ull * 2);      // rope'd k [4096,64]
    f16* vg   = (f16*)alloc(262144ull * 2);      // v [4096,64]
    f16* ao   = (f16*)alloc(4194304ull * 2);     // attn out [4096,1024]
    // partial: 1024 slots x 8704B = 8.91MB, aliases xb+Wall (both dead after the QKV GEMM)
    char* partial = (char*)xb;

    cvt_all_kernel<<<6272, 256, 0, stream>>>(x, Wq, Wk, Wv, Wo, xb, Wall, Wob);
    gemm_f16<2><<<dim3(9, 32), 256, 0, stream>>>(xb, Wall, qg, krp, vg, 4096, 1152, 1024, 1024);
    attn_kernel<<<dim3(48, 32), 256, 0, stream>>>(qg, krp, vg, ao, partial);
    combine_kernel<<<dim3(16, 32), 256, 0, stream>>>(partial, ao);
    gemm_f16<1><<<dim3(8, 32), 256, 0, stream>>>(ao, Wob, out, nullptr, nullptr, 4096, 1024, 1024, 1024);
}

// Round 5
// 118.982 us; speedup vs baseline: 2.8151x; 1.7930x over previous
//
#include <hip/hip_runtime.h>
#include <hip/hip_bf16.h>

typedef _Float16 f16;
typedef __attribute__((ext_vector_type(8))) _Float16 f16x8;
typedef __attribute__((ext_vector_type(4))) _Float16 f16x4;
typedef __attribute__((ext_vector_type(4))) float f32x4;

#define MFMA16(a, b, c) __builtin_amdgcn_mfma_f32_16x16x32_f16(a, b, c, 0, 0, 0)

__device__ __forceinline__ void gload_lds16(const void* g, void* l)
{
    __builtin_amdgcn_global_load_lds(
        (const __attribute__((address_space(1))) unsigned int*)g,
        (__attribute__((address_space(3))) unsigned int*)l, 16, 0, 0);
}

// ---------------- merged convert: x -> f16; weights -> f16 TRANSPOSED [N][K] ----------------
// thread ranges: [0,1048576) x ; [1048576,1114112) Wq->WallT rows 0..1023 ;
// [1114112,1122304) Wk|Wv->WallT rows 1024..1151 (K-head rows permuted p^48 for middle blocks) ;
// [1122304,1187840) Wo->WoT
__global__ __launch_bounds__(256) void cvt_all_kernel(const float* __restrict__ x, const float* __restrict__ Wq,
                                                      const float* __restrict__ Wk, const float* __restrict__ Wv,
                                                      const float* __restrict__ Wo, f16* __restrict__ xb,
                                                      f16* __restrict__ WallT, f16* __restrict__ WoT)
{
    int i = blockIdx.x * 256 + threadIdx.x;
    if (i < 1048576) {
        float4 v = ((const float4*)x)[i];
        f16x4 o;
        o[0] = (f16)v.x; o[1] = (f16)v.y; o[2] = (f16)v.z; o[3] = (f16)v.w;
        *(f16x4*)(xb + 4 * (size_t)i) = o;
        return;
    }
    const float* src;
    f16* dstbase;
    int n4, k4, ldN;
    if (i < 1114112) {
        int j = i - 1048576;
        n4 = (j & 255) * 4; k4 = (j >> 8) * 4;
        src = Wq; ldN = 1024; dstbase = WallT + (size_t)n4 * 1024;
    } else if (i < 1122304) {
        int j = i - 1114112;
        int p4 = (j & 31) * 4; k4 = (j >> 5) * 4;
        if (p4 < 64) {  // K head: permute so rope pairs are intra-wave in the GEMM epilogue
            n4 = (p4 >= 16 && p4 < 48) ? (p4 ^ 48) : p4;
            src = Wk;
        } else {
            n4 = p4 - 64;
            src = Wv;
        }
        ldN = 64; dstbase = WallT + (size_t)(1024 + p4) * 1024;
    } else {
        int j = i - 1122304;
        n4 = (j & 255) * 4; k4 = (j >> 8) * 4;
        src = Wo; ldN = 1024; dstbase = WoT + (size_t)n4 * 1024;
    }
    float4 v0 = *(const float4*)(src + (size_t)(k4 + 0) * ldN + n4);
    float4 v1 = *(const float4*)(src + (size_t)(k4 + 1) * ldN + n4);
    float4 v2 = *(const float4*)(src + (size_t)(k4 + 2) * ldN + n4);
    float4 v3 = *(const float4*)(src + (size_t)(k4 + 3) * ldN + n4);
    float a0[4] = {v0.x, v0.y, v0.z, v0.w};
    float a1[4] = {v1.x, v1.y, v1.z, v1.w};
    float a2[4] = {v2.x, v2.y, v2.z, v2.w};
    float a3[4] = {v3.x, v3.y, v3.z, v3.w};
#pragma unroll
    for (int jj = 0; jj < 4; ++jj) {
        f16x4 o;
        o[0] = (f16)a0[jj]; o[1] = (f16)a1[jj]; o[2] = (f16)a2[jj]; o[3] = (f16)a3[jj];
        *(f16x4*)(dstbase + (size_t)jj * 1024 + k4) = o;
    }
}

// ---------------- f16 GEMM with B^T input: C[M,N] = A[M,K] @ Bt[N,K]^T ----------------
// M=4096, K=1024 fixed. BM=128, BN=64, BK=64. 256 threads = 4 waves 2x2 (wave tile 64x32).
// global_load_lds staging, pre-swizzled source (slot ^= row&7), linear LDS, swizzled b128 reads.
// MODE 0: QKV — bx<16: f16 C (stride 1024); bx==16: rope'd K; bx==17: V. MODE 1: f32 C out.
template<int MODE>
__global__ __launch_bounds__(256) void gemm_bt(const f16* __restrict__ A, const f16* __restrict__ Bt,
                                               void* __restrict__ Cv, f16* __restrict__ kout, f16* __restrict__ vout,
                                               int NBX)
{
    __shared__ __align__(16) f16 As[128 * 64];
    __shared__ __align__(16) f16 Bs[64 * 64];
    int id = blockIdx.x;
    int qn = gridDim.x >> 3;                     // XCD chunk size (grid % 8 == 0)
    int lin = (id & 7) * qn + (id >> 3);         // bijective XCD-aware swizzle
    int bx = lin % NBX, by = lin / NBX;
    int tid = threadIdx.x, lane = tid & 63, wid = tid >> 6;
    int wr = wid >> 1, wc = wid & 1;
    int lrow = lane & 15, gq = lane >> 4;
    f32x4 acc[4][2];
#pragma unroll
    for (int fm = 0; fm < 4; ++fm)
#pragma unroll
        for (int fn = 0; fn < 2; ++fn) acc[fm][fn] = (f32x4){0.f, 0.f, 0.f, 0.f};

    for (int kt = 0; kt < 16; ++kt) {
        int k0 = kt * 64;
        // stage A tile [128][64]: 16 x 1KB chunks, wave wid owns chunks wid*4..+4
#pragma unroll
        for (int i = 0; i < 4; ++i) {
            int c = wid * 4 + i;
            int row = c * 8 + (lane >> 3);
            int slot = (lane & 7) ^ (row & 7);
            gload_lds16(A + (size_t)(by * 128 + row) * 1024 + k0 + slot * 8, &As[c * 512 + lane * 8]);
        }
        // stage B tile [64][64]: 8 chunks, wave wid owns chunks wid*2..+2
#pragma unroll
        for (int i = 0; i < 2; ++i) {
            int c = wid * 2 + i;
            int row = c * 8 + (lane >> 3);
            int slot = (lane & 7) ^ (row & 7);
            gload_lds16(Bt + (size_t)(bx * 64 + row) * 1024 + k0 + slot * 8, &Bs[c * 512 + lane * 8]);
        }
        __syncthreads();
#pragma unroll
        for (int ks = 0; ks < 2; ++ks) {
            f16x8 af[4], bf[2];
#pragma unroll
            for (int fm = 0; fm < 4; ++fm) {
                int row = wr * 64 + fm * 16 + lrow;
                int slot = (ks * 4 + gq) ^ (row & 7);
                af[fm] = *(const f16x8*)&As[row * 64 + slot * 8];
            }
#pragma unroll
            for (int fn = 0; fn < 2; ++fn) {
                int row = wc * 32 + fn * 16 + lrow;
                int slot = (ks * 4 + gq) ^ (row & 7);
                bf[fn] = *(const f16x8*)&Bs[row * 64 + slot * 8];
            }
#pragma unroll
            for (int fm = 0; fm < 4; ++fm)
#pragma unroll
                for (int fn = 0; fn < 2; ++fn)
                    acc[fm][fn] = MFMA16(af[fm], bf[fn], acc[fm][fn]);
        }
        __syncthreads();
    }
    // epilogue: C/D layout col=lane&15, row=(lane>>4)*4+reg
    if constexpr (MODE == 1) {
        float* C = (float*)Cv;
#pragma unroll
        for (int fm = 0; fm < 4; ++fm)
#pragma unroll
            for (int fn = 0; fn < 2; ++fn)
#pragma unroll
                for (int r = 0; r < 4; ++r) {
                    int row = by * 128 + wr * 64 + fm * 16 + gq * 4 + r;
                    int col = bx * 64 + wc * 32 + fn * 16 + lrow;
                    C[(size_t)row * 1024 + col] = acc[fm][fn][r];
                }
    } else {
        if (bx < 16) {
            f16* C = (f16*)Cv;
#pragma unroll
            for (int fm = 0; fm < 4; ++fm)
#pragma unroll
                for (int fn = 0; fn < 2; ++fn)
#pragma unroll
                    for (int r = 0; r < 4; ++r) {
                        int row = by * 128 + wr * 64 + fm * 16 + gq * 4 + r;
                        int col = bx * 64 + wc * 32 + fn * 16 + lrow;
                        C[(size_t)row * 1024 + col] = (f16)acc[fm][fn][r];
                    }
        } else if (bx == 16) {
            // K head with rope. Weight-permutation makes wave wc own pair (i, i+32) for i = wc*16+lrow:
            // fn=0 holds x1 (dim i), fn=1 holds x2 (dim i+32).
            const float L2B = 13.287712379549449f / 64.0f;
            int i = wc * 16 + lrow;
            float invf = exp2f(-(float)(2 * i) * L2B);
#pragma unroll
            for (int fm = 0; fm < 4; ++fm)
#pragma unroll
                for (int r = 0; r < 4; ++r) {
                    int row = by * 128 + wr * 64 + fm * 16 + gq * 4 + r;
                    float t = (float)(row & 2047);
                    float ss, cc;
                    sincosf(t * invf, &ss, &cc);
                    float x1 = acc[fm][0][r], x2 = acc[fm][1][r];
                    kout[(size_t)row * 64 + i]      = (f16)(x1 * cc - x2 * ss);
                    kout[(size_t)row * 64 + i + 32] = (f16)(x2 * cc + x1 * ss);
                }
        } else {
#pragma unroll
            for (int fm = 0; fm < 4; ++fm)
#pragma unroll
                for (int fn = 0; fn < 2; ++fn)
#pragma unroll
                    for (int r = 0; r < 4; ++r) {
                        int row = by * 128 + wr * 64 + fm * 16 + gq * 4 + r;
                        vout[(size_t)row * 64 + wc * 32 + fn * 16 + lrow] = (f16)acc[fm][fn][r];
                    }
        }
    }
}

// ---------------- causal MQA flash attention ----------------
// Swapped QK^T (P[key][qrow] in-lane softmax), XOR-swizzled LDS, double-buffered K/V, 1 barrier/tile.
// q: [B*T,1024] raw proj (rope fused here); k: [B*T,64] rope'd; v: [B*T,64]
// grid (48,32): c<32 -> qt=31-(c>>1), 2 key-chunks; c>=32 -> qt=47-c single chunk.
__global__ __launch_bounds__(256, 3) void attn_kernel(const f16* __restrict__ q, const f16* __restrict__ k,
                                                      const f16* __restrict__ v, f16* __restrict__ ao,
                                                      char* __restrict__ partial)
{
    constexpr int T = 2048;
    int c = blockIdx.x, bh = blockIdx.y;
    int b = bh >> 4, h = bh & 15;
    int qt, ch, nch;
    if (c < 32) { qt = 31 - (c >> 1); ch = c & 1; nch = 2; }
    else        { qt = 47 - c; ch = 0; nch = 1; }
    int ntiles = qt + 1;
    int tbeg = ch * 16;
    int tend = (nch == 2 && ch == 0) ? 16 : ntiles;

    int tid = threadIdx.x, lane = tid & 63, wid = tid >> 6;
    int lrow = lane & 15, g = lane >> 4;
    int qw = qt * 64 + wid * 16;
    int swl = (lrow & 7) << 3;     // read-side swizzle (all read rows ≡ lrow mod 8)

    __shared__ f16 KsB[2][64 * 64];
    __shared__ f16 VtB[2][64 * 64];
    __shared__ f16 PsB[4][16 * 64];

    // Q load + inline rope + scale (0.125*log2e folded; softmax in exp2 space)
    const f16* qrow = q + (size_t)(b * T + qw + lrow) * 1024 + h * 64;
    f16x8 x0 = *(const f16x8*)&qrow[g * 8];
    f16x8 x1 = *(const f16x8*)&qrow[g * 8 + 32];
    f16x8 qf0, qf1;
    {
        const float qsc = 0.125f * 1.4426950408889634f;
        const float L2B = 13.287712379549449f / 64.0f;
        float t_ = (float)(qw + lrow);
#pragma unroll
        for (int j = 0; j < 8; ++j) {
            int i = g * 8 + j;
            float invf = exp2f(-(float)(2 * i) * L2B);
            float ss, cc;
            sincosf(t_ * invf, &ss, &cc);
            float a0 = (float)x0[j], a1 = (float)x1[j];
            qf0[j] = (f16)((a0 * cc - a1 * ss) * qsc);
            qf1[j] = (f16)((a1 * cc + a0 * ss) * qsc);
        }
    }

    float m = -1e30f, l = 0.f;
    f32x4 o[4];
#pragma unroll
    for (int dt = 0; dt < 4; ++dt) o[dt] = (f32x4){0.f, 0.f, 0.f, 0.f};

    int skr = wid * 16 + (lane >> 2);
    int skc = (lane & 3) * 16;
    int swk = (skr & 7) << 3;
    const f16* kbase = k + (size_t)b * T * 64;
    const f16* vbase = v + (size_t)b * T * 64;

    // prologue: stage tile tbeg -> buf 0
    {
        const f16* kb = kbase + (size_t)(tbeg * 64 + skr) * 64 + skc;
        *(f16x8*)&KsB[0][skr * 64 + (skc ^ swk)]       = ((const f16x8*)kb)[0];
        *(f16x8*)&KsB[0][skr * 64 + ((skc + 8) ^ swk)] = ((const f16x8*)kb)[1];
        const f16* vb = vbase + (size_t)(tbeg * 64 + lane) * 64 + wid * 16;
        f16x8 vv0 = ((const f16x8*)vb)[0];
        f16x8 vv1 = ((const f16x8*)vb)[1];
#pragma unroll
        for (int j = 0; j < 8; ++j) {
            VtB[0][(wid * 16 + j) * 64 + (lane ^ (j << 3))]     = vv0[j];
            VtB[0][(wid * 16 + 8 + j) * 64 + (lane ^ (j << 3))] = vv1[j];
        }
    }
    __syncthreads();

    for (int t = tbeg; t < tend; ++t) {
        int cur = (t - tbeg) & 1;
        bool hasnext = (t + 1 < tend);
        f16x8 kn0, kn1, vn0, vn1;
        if (hasnext) {                       // prefetch next tile into regs (latency hidden by compute)
            const f16* kb = kbase + (size_t)((t + 1) * 64 + skr) * 64 + skc;
            kn0 = ((const f16x8*)kb)[0];
            kn1 = ((const f16x8*)kb)[1];
            const f16* vb = vbase + (size_t)((t + 1) * 64 + lane) * 64 + wid * 16;
            vn0 = ((const f16x8*)vb)[0];
            vn1 = ((const f16x8*)vb)[1];
        }
        const f16* Ks = KsB[cur];
        const f16* Vt = VtB[cur];
        f16* Ps = PsB[wid];

        // S^T = K Q : D[key][qrow]; lane holds keys tt*16+g*4+r for q-row lrow
        f32x4 s[4];
#pragma unroll
        for (int tt = 0; tt < 4; ++tt) {
            f16x8 kf0 = *(const f16x8*)&Ks[(tt * 16 + lrow) * 64 + ((g * 8) ^ swl)];
            f16x8 kf1 = *(const f16x8*)&Ks[(tt * 16 + lrow) * 64 + ((32 + g * 8) ^ swl)];
            f32x4 z = (f32x4){0.f, 0.f, 0.f, 0.f};
            z = MFMA16(kf0, qf0, z);
            z = MFMA16(kf1, qf1, z);
            s[tt] = z;
        }
        if (t == ntiles - 1) {               // causal mask, diagonal tile only
            int qab = qw + lrow;
            int kb0 = t * 64 + g * 4;
#pragma unroll
            for (int tt = 0; tt < 4; ++tt)
#pragma unroll
                for (int r = 0; r < 4; ++r)
                    if (kb0 + tt * 16 + r > qab) s[tt][r] = -1e30f;
        }
        // in-lane max tree + 2 cross-lane ops
        float mx0 = fmaxf(fmaxf(s[0][0], s[0][1]), fmaxf(s[0][2], s[0][3]));
        float mx1 = fmaxf(fmaxf(s[1][0], s[1][1]), fmaxf(s[1][2], s[1][3]));
        float mx2 = fmaxf(fmaxf(s[2][0], s[2][1]), fmaxf(s[2][2], s[2][3]));
        float mx3 = fmaxf(fmaxf(s[3][0], s[3][1]), fmaxf(s[3][2], s[3][3]));
        float mx = fmaxf(fmaxf(mx0, mx1), fmaxf(mx2, mx3));
        mx = fmaxf(mx, __shfl_xor(mx, 16));
        mx = fmaxf(mx, __shfl_xor(mx, 32));
        float mn = fmaxf(m, mx);
        float alpha = exp2f(m - mn);
        m = mn;
        float rs = 0.f;
#pragma unroll
        for (int tt = 0; tt < 4; ++tt) {
            f16x4 pw;
#pragma unroll
            for (int r = 0; r < 4; ++r) {
                float p = exp2f(s[tt][r] - mn);
                s[tt][r] = p;
                pw[r] = (f16)p;
            }
            rs += (s[tt][0] + s[tt][1]) + (s[tt][2] + s[tt][3]);
            *(f16x4*)&Ps[lrow * 64 + ((tt * 16 + g * 4) ^ swl)] = pw;
        }
        l = l * alpha + rs;
        // broadcast alpha to the o-rows this lane owns (rows g*4+rr)
        float av0 = __shfl(alpha, g * 4 + 0);
        float av1 = __shfl(alpha, g * 4 + 1);
        float av2 = __shfl(alpha, g * 4 + 2);
        float av3 = __shfl(alpha, g * 4 + 3);
#pragma unroll
        for (int dt = 0; dt < 4; ++dt) {
            o[dt][0] *= av0; o[dt][1] *= av1; o[dt][2] *= av2; o[dt][3] *= av3;
        }
        // PV (same-wave Ps roundtrip; compiler inserts lgkmcnt)
#pragma unroll
        for (int chk = 0; chk < 2; ++chk) {
            f16x8 pf = *(const f16x8*)&Ps[lrow * 64 + ((chk * 32 + g * 8) ^ swl)];
#pragma unroll
            for (int dt = 0; dt < 4; ++dt) {
                f16x8 vf = *(const f16x8*)&Vt[(dt * 16 + lrow) * 64 + ((chk * 32 + g * 8) ^ swl)];
                o[dt] = MFMA16(pf, vf, o[dt]);
            }
        }
        // stage next tile into other buffer (read by no one until the barrier)
        if (hasnext) {
            int nb = cur ^ 1;
            *(f16x8*)&KsB[nb][skr * 64 + (skc ^ swk)]       = kn0;
            *(f16x8*)&KsB[nb][skr * 64 + ((skc + 8) ^ swk)] = kn1;
#pragma unroll
            for (int j = 0; j < 8; ++j) {
                VtB[nb][(wid * 16 + j) * 64 + (lane ^ (j << 3))]     = vn0[j];
                VtB[nb][(wid * 16 + 8 + j) * 64 + (lane ^ (j << 3))] = vn1[j];
            }
        }
        __syncthreads();
    }
    // finish the deferred row-sum
    l += __shfl_xor(l, 16);
    l += __shfl_xor(l, 32);
    float lv[4];
#pragma unroll
    for (int rr = 0; rr < 4; ++rr) lv[rr] = __shfl(l, g * 4 + rr);

    if (nch == 1) {
#pragma unroll
        for (int rr = 0; rr < 4; ++rr) {
            float inv = 1.f / lv[rr];
            int qab = qw + g * 4 + rr;
#pragma unroll
            for (int dt = 0; dt < 4; ++dt)
                ao[(size_t)(b * T + qab) * 1024 + h * 64 + dt * 16 + lrow] = (f16)(o[dt][rr] * inv);
        }
    } else {
        char* slot = partial + ((size_t)(bh * 16 + (qt - 16)) * 2 + ch) * 8704;
        f16* op = (f16*)slot;
        float* mp = (float*)(slot + 8192);
        float* lp = mp + 64;
#pragma unroll
        for (int rr = 0; rr < 4; ++rr) {
            int row = wid * 16 + g * 4 + rr;
#pragma unroll
            for (int dt = 0; dt < 4; ++dt)
                op[row * 64 + dt * 16 + lrow] = (f16)o[dt][rr];
        }
        if (g == 0) { mp[wid * 16 + lrow] = m; lp[wid * 16 + lrow] = l; }
    }
}

// ---------------- combine partials (2 chunks) for qt>=16 ----------------
__global__ __launch_bounds__(256) void combine_kernel(const char* __restrict__ partial, f16* __restrict__ ao)
{
    constexpr int T = 2048;
    int qt = 16 + blockIdx.x, bh = blockIdx.y;
    int b = bh >> 4, h = bh & 15;
    int tid = threadIdx.x;
    int row = tid >> 2, dp = (tid & 3) * 16;
    const char* s0 = partial + ((size_t)(bh * 16 + (qt - 16)) * 2) * 8704;
    const char* s1 = s0 + 8704;
    const f16* o0 = (const f16*)s0; const float* m0 = (const float*)(s0 + 8192); const float* l0 = m0 + 64;
    const f16* o1 = (const f16*)s1; const float* m1 = (const float*)(s1 + 8192); const float* l1 = m1 + 64;
    float mm0 = m0[row], mm1 = m1[row];
    float M = fmaxf(mm0, mm1);
    float a0 = exp2f(mm0 - M), a1 = exp2f(mm1 - M);
    float inv = 1.f / (l0[row] * a0 + l1[row] * a1);
    f16x8 u0 = ((const f16x8*)(o0 + row * 64 + dp))[0];
    f16x8 u1 = ((const f16x8*)(o0 + row * 64 + dp))[1];
    f16x8 w0 = ((const f16x8*)(o1 + row * 64 + dp))[0];
    f16x8 w1 = ((const f16x8*)(o1 + row * 64 + dp))[1];
    f16x8 r0, r1;
#pragma unroll
    for (int j = 0; j < 8; ++j) {
        r0[j] = (f16)(((float)u0[j] * a0 + (float)w0[j] * a1) * inv);
        r1[j] = (f16)(((float)u1[j] * a0 + (float)w1[j] * a1) * inv);
    }
    f16* dst = ao + (size_t)(b * T + qt * 64 + row) * 1024 + h * 64 + dp;
    *(f16x8*)dst = r0;
    *(f16x8*)(dst + 8) = r1;
}

extern "C" void kernel_launch(void* const* d_in, const int* in_sizes, int n_in,
                              void* d_out, int out_size, void* d_ws, size_t ws_size,
                              hipStream_t stream)
{
    (void)in_sizes; (void)n_in; (void)out_size; (void)ws_size;
    const float* x  = (const float*)d_in[0];
    const float* Wq = (const float*)d_in[1];
    const float* Wk = (const float*)d_in[2];
    const float* Wv = (const float*)d_in[3];
    const float* Wo = (const float*)d_in[4];
    float* out = (float*)d_out;

    char* w = (char*)d_ws;
    size_t off = 0;
    auto alloc = [&](size_t bytes) -> void* {
        void* p = (void*)(w + off);
        off += (bytes + 255) & ~(size_t)255;
        return p;
    };
    f16* xb    = (f16*)alloc(4194304ull * 2);    // x f16 [4096,1024] (reused as attn partial buffer)
    f16* WallT = (f16*)alloc(1179648ull * 2);    // [1152,1024] = (Wq|Wk_perm|Wv)^T  (partial overflow region)
    f16* WoT   = (f16*)alloc(1048576ull * 2);    // Wo^T [1024,1024]
    f16* qg    = (f16*)alloc(4194304ull * 2);    // q proj [4096,1024] (rope fused in attn)
    f16* krp   = (f16*)alloc(262144ull * 2);     // rope'd k [4096,64]
    f16* vg    = (f16*)alloc(262144ull * 2);     // v [4096,64]
    f16* ao    = (f16*)alloc(4194304ull * 2);    // attn out [4096,1024]
    // partial: 1024 slots x 8704B = 8.91MB, aliases xb+WallT (both dead after the QKV GEMM)
    char* partial = (char*)xb;

    cvt_all_kernel<<<4640, 256, 0, stream>>>(x, Wq, Wk, Wv, Wo, xb, WallT, WoT);
    gemm_bt<0><<<576, 256, 0, stream>>>(xb, WallT, qg, krp, vg, 18);
    attn_kernel<<<dim3(48, 32), 256, 0, stream>>>(qg, krp, vg, ao, partial);
    combine_kernel<<<dim3(16, 32), 256, 0, stream>>>(partial, ao);
    gemm_bt<1><<<512, 256, 0, stream>>>(ao, WoT, out, nullptr, nullptr, 16);
}

// Round 6
// 108.215 us; speedup vs baseline: 3.0952x; 1.0995x over previous
//
#include <hip/hip_runtime.h>
#include <hip/hip_bf16.h>

typedef _Float16 f16;
typedef __attribute__((ext_vector_type(8))) _Float16 f16x8;
typedef __attribute__((ext_vector_type(4))) _Float16 f16x4;
typedef __attribute__((ext_vector_type(4))) float f32x4;

#define MFMA16(a, b, c) __builtin_amdgcn_mfma_f32_16x16x32_f16(a, b, c, 0, 0, 0)

__device__ __forceinline__ void gload_lds16(const void* g, void* l)
{
    __builtin_amdgcn_global_load_lds(
        (const __attribute__((address_space(1))) unsigned int*)g,
        (__attribute__((address_space(3))) unsigned int*)l, 16, 0, 0);
}

// ---------------- merged convert: x -> f16; weights -> f16 TRANSPOSED [N][K] ----------------
__global__ __launch_bounds__(256) void cvt_all_kernel(const float* __restrict__ x, const float* __restrict__ Wq,
                                                      const float* __restrict__ Wk, const float* __restrict__ Wv,
                                                      const float* __restrict__ Wo, f16* __restrict__ xb,
                                                      f16* __restrict__ WallT, f16* __restrict__ WoT)
{
    int i = blockIdx.x * 256 + threadIdx.x;
    if (i < 1048576) {
        float4 v = ((const float4*)x)[i];
        f16x4 o;
        o[0] = (f16)v.x; o[1] = (f16)v.y; o[2] = (f16)v.z; o[3] = (f16)v.w;
        *(f16x4*)(xb + 4 * (size_t)i) = o;
        return;
    }
    const float* src;
    f16* dstbase;
    int n4, k4, ldN;
    if (i < 1114112) {
        int j = i - 1048576;
        n4 = (j & 255) * 4; k4 = (j >> 8) * 4;
        src = Wq; ldN = 1024; dstbase = WallT + (size_t)n4 * 1024;
    } else if (i < 1122304) {
        int j = i - 1114112;
        int p4 = (j & 31) * 4; k4 = (j >> 5) * 4;
        if (p4 < 64) {  // K head: permute so rope pairs are intra-wave in the GEMM epilogue
            n4 = (p4 >= 16 && p4 < 48) ? (p4 ^ 48) : p4;
            src = Wk;
        } else {
            n4 = p4 - 64;
            src = Wv;
        }
        ldN = 64; dstbase = WallT + (size_t)(1024 + p4) * 1024;
    } else {
        int j = i - 1122304;
        n4 = (j & 255) * 4; k4 = (j >> 8) * 4;
        src = Wo; ldN = 1024; dstbase = WoT + (size_t)n4 * 1024;
    }
    float4 v0 = *(const float4*)(src + (size_t)(k4 + 0) * ldN + n4);
    float4 v1 = *(const float4*)(src + (size_t)(k4 + 1) * ldN + n4);
    float4 v2 = *(const float4*)(src + (size_t)(k4 + 2) * ldN + n4);
    float4 v3 = *(const float4*)(src + (size_t)(k4 + 3) * ldN + n4);
    float a0[4] = {v0.x, v0.y, v0.z, v0.w};
    float a1[4] = {v1.x, v1.y, v1.z, v1.w};
    float a2[4] = {v2.x, v2.y, v2.z, v2.w};
    float a3[4] = {v3.x, v3.y, v3.z, v3.w};
#pragma unroll
    for (int jj = 0; jj < 4; ++jj) {
        f16x4 o;
        o[0] = (f16)a0[jj]; o[1] = (f16)a1[jj]; o[2] = (f16)a2[jj]; o[3] = (f16)a3[jj];
        *(f16x4*)(dstbase + (size_t)jj * 1024 + k4) = o;
    }
}

// ---------------- f16 GEMM with B^T input (unchanged from round 5) ----------------
template<int MODE>
__global__ __launch_bounds__(256) void gemm_bt(const f16* __restrict__ A, const f16* __restrict__ Bt,
                                               void* __restrict__ Cv, f16* __restrict__ kout, f16* __restrict__ vout,
                                               int NBX)
{
    __shared__ __align__(16) f16 As[128 * 64];
    __shared__ __align__(16) f16 Bs[64 * 64];
    int id = blockIdx.x;
    int qn = gridDim.x >> 3;
    int lin = (id & 7) * qn + (id >> 3);
    int bx = lin % NBX, by = lin / NBX;
    int tid = threadIdx.x, lane = tid & 63, wid = tid >> 6;
    int wr = wid >> 1, wc = wid & 1;
    int lrow = lane & 15, gq = lane >> 4;
    f32x4 acc[4][2];
#pragma unroll
    for (int fm = 0; fm < 4; ++fm)
#pragma unroll
        for (int fn = 0; fn < 2; ++fn) acc[fm][fn] = (f32x4){0.f, 0.f, 0.f, 0.f};

    for (int kt = 0; kt < 16; ++kt) {
        int k0 = kt * 64;
#pragma unroll
        for (int i = 0; i < 4; ++i) {
            int c = wid * 4 + i;
            int row = c * 8 + (lane >> 3);
            int slot = (lane & 7) ^ (row & 7);
            gload_lds16(A + (size_t)(by * 128 + row) * 1024 + k0 + slot * 8, &As[c * 512 + lane * 8]);
        }
#pragma unroll
        for (int i = 0; i < 2; ++i) {
            int c = wid * 2 + i;
            int row = c * 8 + (lane >> 3);
            int slot = (lane & 7) ^ (row & 7);
            gload_lds16(Bt + (size_t)(bx * 64 + row) * 1024 + k0 + slot * 8, &Bs[c * 512 + lane * 8]);
        }
        __syncthreads();
#pragma unroll
        for (int ks = 0; ks < 2; ++ks) {
            f16x8 af[4], bf[2];
#pragma unroll
            for (int fm = 0; fm < 4; ++fm) {
                int row = wr * 64 + fm * 16 + lrow;
                int slot = (ks * 4 + gq) ^ (row & 7);
                af[fm] = *(const f16x8*)&As[row * 64 + slot * 8];
            }
#pragma unroll
            for (int fn = 0; fn < 2; ++fn) {
                int row = wc * 32 + fn * 16 + lrow;
                int slot = (ks * 4 + gq) ^ (row & 7);
                bf[fn] = *(const f16x8*)&Bs[row * 64 + slot * 8];
            }
#pragma unroll
            for (int fm = 0; fm < 4; ++fm)
#pragma unroll
                for (int fn = 0; fn < 2; ++fn)
                    acc[fm][fn] = MFMA16(af[fm], bf[fn], acc[fm][fn]);
        }
        __syncthreads();
    }
    if constexpr (MODE == 1) {
        float* C = (float*)Cv;
#pragma unroll
        for (int fm = 0; fm < 4; ++fm)
#pragma unroll
            for (int fn = 0; fn < 2; ++fn)
#pragma unroll
                for (int r = 0; r < 4; ++r) {
                    int row = by * 128 + wr * 64 + fm * 16 + gq * 4 + r;
                    int col = bx * 64 + wc * 32 + fn * 16 + lrow;
                    C[(size_t)row * 1024 + col] = acc[fm][fn][r];
                }
    } else {
        if (bx < 16) {
            f16* C = (f16*)Cv;
#pragma unroll
            for (int fm = 0; fm < 4; ++fm)
#pragma unroll
                for (int fn = 0; fn < 2; ++fn)
#pragma unroll
                    for (int r = 0; r < 4; ++r) {
                        int row = by * 128 + wr * 64 + fm * 16 + gq * 4 + r;
                        int col = bx * 64 + wc * 32 + fn * 16 + lrow;
                        C[(size_t)row * 1024 + col] = (f16)acc[fm][fn][r];
                    }
        } else if (bx == 16) {
            const float L2B = 13.287712379549449f / 64.0f;
            int i = wc * 16 + lrow;
            float invf = exp2f(-(float)(2 * i) * L2B);
#pragma unroll
            for (int fm = 0; fm < 4; ++fm)
#pragma unroll
                for (int r = 0; r < 4; ++r) {
                    int row = by * 128 + wr * 64 + fm * 16 + gq * 4 + r;
                    float t = (float)(row & 2047);
                    float ss, cc;
                    sincosf(t * invf, &ss, &cc);
                    float x1 = acc[fm][0][r], x2 = acc[fm][1][r];
                    kout[(size_t)row * 64 + i]      = (f16)(x1 * cc - x2 * ss);
                    kout[(size_t)row * 64 + i + 32] = (f16)(x2 * cc + x1 * ss);
                }
        } else {
#pragma unroll
            for (int fm = 0; fm < 4; ++fm)
#pragma unroll
                for (int fn = 0; fn < 2; ++fn)
#pragma unroll
                    for (int r = 0; r < 4; ++r) {
                        int row = by * 128 + wr * 64 + fm * 16 + gq * 4 + r;
                        vout[(size_t)row * 64 + wc * 32 + fn * 16 + lrow] = (f16)acc[fm][fn][r];
                    }
        }
    }
}

// ---------------- causal MQA flash attention: 128 q-rows/block, 32/wave ----------------
// Job table: (p, ch) chunks of <=16 key-tiles, ordered big-first. p = q-tile of 128 rows,
// ntiles = 2p+2, nch = ceil(nt/16). nch==1 writes ao; nch==2 writes 128-row partial slots.
__device__ __constant__ signed char TBL_P[24]  = {7,8,9,10,11,12,13,14,15,15,14,6,13,5,12,4,11,3,10,2,9,1,8,0};
__device__ __constant__ signed char TBL_CH[24] = {0,0,0, 0, 0, 0, 0, 0, 0, 1, 1,0, 1,0, 1,0, 1,0, 1,0,1,0,1,0};

// defer-max softmax for one fragment (S = f32x4[4], per-lane q-row = lrow)
#define SOFTMAX(S, MM, LL, OO, PSF) do {                                            \
    float mx = fmaxf(fmaxf(fmaxf(S[0][0],S[0][1]),fmaxf(S[0][2],S[0][3])),          \
                     fmaxf(fmaxf(S[1][0],S[1][1]),fmaxf(S[1][2],S[1][3])));         \
    mx = fmaxf(mx, fmaxf(fmaxf(fmaxf(S[2][0],S[2][1]),fmaxf(S[2][2],S[2][3])),      \
                         fmaxf(fmaxf(S[3][0],S[3][1]),fmaxf(S[3][2],S[3][3]))));    \
    mx = fmaxf(mx, __shfl_xor(mx, 16));                                             \
    mx = fmaxf(mx, __shfl_xor(mx, 32));                                             \
    if (!__all(mx <= MM + 3.0f)) {                                                  \
        float mn = fmaxf(MM, mx);                                                   \
        float alpha = exp2f(MM - mn);                                               \
        MM = mn; LL *= alpha;                                                       \
        float av0 = __shfl(alpha, g * 4 + 0), av1 = __shfl(alpha, g * 4 + 1);       \
        float av2 = __shfl(alpha, g * 4 + 2), av3 = __shfl(alpha, g * 4 + 3);       \
        _Pragma("unroll")                                                           \
        for (int dt = 0; dt < 4; ++dt) {                                            \
            OO[dt][0] *= av0; OO[dt][1] *= av1; OO[dt][2] *= av2; OO[dt][3] *= av3; \
        }                                                                           \
    }                                                                               \
    float rs = 0.f;                                                                 \
    _Pragma("unroll")                                                               \
    for (int tt = 0; tt < 4; ++tt) {                                                \
        f16x4 pw;                                                                   \
        _Pragma("unroll")                                                           \
        for (int r = 0; r < 4; ++r) {                                               \
            float pp = exp2f(S[tt][r] - MM); S[tt][r] = pp; pw[r] = (f16)pp;        \
        }                                                                           \
        rs += (S[tt][0] + S[tt][1]) + (S[tt][2] + S[tt][3]);                        \
        *(f16x4*)&PSF[lrow * 64 + ((tt * 16 + g * 4) ^ swl)] = pw;                  \
    }                                                                               \
    LL += rs;                                                                       \
} while (0)

__global__ __launch_bounds__(256, 3) void attn_kernel(const f16* __restrict__ q, const f16* __restrict__ k,
                                                      const f16* __restrict__ v, f16* __restrict__ ao,
                                                      char* __restrict__ partial)
{
    constexpr int T = 2048;
    int c = blockIdx.x, bh = blockIdx.y;
    int b = bh >> 4, h = bh & 15;
    int p = TBL_P[c], ch = TBL_CH[c];
    int nt = 2 * p + 2;
    int nch = (nt + 15) >> 4;
    int tbeg = ch * 16;
    int tend = min(nt, tbeg + 16);

    int tid = threadIdx.x, lane = tid & 63, wid = tid >> 6;
    int lrow = lane & 15, g = lane >> 4;
    int qb = p * 128;
    int qw = qb + wid * 32;                    // wave's first q-row (owns 32)
    int tdiag = 2 * p + (wid >> 1);            // wave's diagonal tile
    int tw_end = tdiag + 1;                    // exclusive compute end
    int swl = (lrow & 7) << 3;

    __shared__ f16 KsB[2][64 * 64];
    __shared__ f16 VtB[2][64 * 64];
    __shared__ f16 PsB[4][2][16 * 64];

    // Q load + inline rope + scale for both fragments
    f16x8 qfA0, qfA1, qfB0, qfB1;
    {
        const f16* qrowA = q + (size_t)(b * T + qw + lrow) * 1024 + h * 64;
        const f16* qrowB = qrowA + 16 * 1024;
        f16x8 xA0 = *(const f16x8*)&qrowA[g * 8];
        f16x8 xA1 = *(const f16x8*)&qrowA[g * 8 + 32];
        f16x8 xB0 = *(const f16x8*)&qrowB[g * 8];
        f16x8 xB1 = *(const f16x8*)&qrowB[g * 8 + 32];
        const float qsc = 0.125f * 1.4426950408889634f;
        const float L2B = 13.287712379549449f / 64.0f;
        float tA = (float)(qw + lrow), tB = (float)(qw + 16 + lrow);
#pragma unroll
        for (int j = 0; j < 8; ++j) {
            int i = g * 8 + j;
            float invf = exp2f(-(float)(2 * i) * L2B);
            float sA, cA, sB, cB;
            sincosf(tA * invf, &sA, &cA);
            sincosf(tB * invf, &sB, &cB);
            float a0 = (float)xA0[j], a1 = (float)xA1[j];
            qfA0[j] = (f16)((a0 * cA - a1 * sA) * qsc);
            qfA1[j] = (f16)((a1 * cA + a0 * sA) * qsc);
            float b0 = (float)xB0[j], b1 = (float)xB1[j];
            qfB0[j] = (f16)((b0 * cB - b1 * sB) * qsc);
            qfB1[j] = (f16)((b1 * cB + b0 * sB) * qsc);
        }
    }

    float mA = -1e30f, lA = 0.f, mB = -1e30f, lB = 0.f;
    f32x4 oA[4], oB[4];
#pragma unroll
    for (int dt = 0; dt < 4; ++dt) { oA[dt] = (f32x4){0.f,0.f,0.f,0.f}; oB[dt] = (f32x4){0.f,0.f,0.f,0.f}; }

    int skr = wid * 16 + (lane >> 2);
    int skc = (lane & 3) * 16;
    int swk = (skr & 7) << 3;
    const f16* kbase = k + (size_t)b * T * 64;
    const f16* vbase = v + (size_t)b * T * 64;

    // prologue: stage tile tbeg -> buf 0
    {
        const f16* kb = kbase + (size_t)(tbeg * 64 + skr) * 64 + skc;
        *(f16x8*)&KsB[0][skr * 64 + (skc ^ swk)]       = ((const f16x8*)kb)[0];
        *(f16x8*)&KsB[0][skr * 64 + ((skc + 8) ^ swk)] = ((const f16x8*)kb)[1];
        const f16* vb = vbase + (size_t)(tbeg * 64 + lane) * 64 + wid * 16;
        f16x8 vv0 = ((const f16x8*)vb)[0];
        f16x8 vv1 = ((const f16x8*)vb)[1];
#pragma unroll
        for (int j = 0; j < 8; ++j) {
            VtB[0][(wid * 16 + j) * 64 + (lane ^ (j << 3))]     = vv0[j];
            VtB[0][(wid * 16 + 8 + j) * 64 + (lane ^ (j << 3))] = vv1[j];
        }
    }
    __syncthreads();

    for (int t = tbeg; t < tend; ++t) {
        int cur = (t - tbeg) & 1;
        bool hasnext = (t + 1 < tend);
        f16x8 kn0, kn1, vn0, vn1;
        if (hasnext) {
            const f16* kb = kbase + (size_t)((t + 1) * 64 + skr) * 64 + skc;
            kn0 = ((const f16x8*)kb)[0];
            kn1 = ((const f16x8*)kb)[1];
            const f16* vb = vbase + (size_t)((t + 1) * 64 + lane) * 64 + wid * 16;
            vn0 = ((const f16x8*)vb)[0];
            vn1 = ((const f16x8*)vb)[1];
        }
        if (t < tw_end) {                      // waves past their diagonal only stage
            const f16* Ks = KsB[cur];
            const f16* Vt = VtB[cur];
            f16* PsA = &PsB[wid][0][0];
            f16* PsBf = &PsB[wid][1][0];

            f32x4 sA[4], sB[4];
#pragma unroll
            for (int tt = 0; tt < 4; ++tt) {
                f16x8 kf0 = *(const f16x8*)&Ks[(tt * 16 + lrow) * 64 + ((g * 8) ^ swl)];
                f16x8 kf1 = *(const f16x8*)&Ks[(tt * 16 + lrow) * 64 + ((32 + g * 8) ^ swl)];
                f32x4 z = (f32x4){0.f, 0.f, 0.f, 0.f};
                z = MFMA16(kf0, qfA0, z);
                z = MFMA16(kf1, qfA1, z);
                sA[tt] = z;
                z = (f32x4){0.f, 0.f, 0.f, 0.f};
                z = MFMA16(kf0, qfB0, z);
                z = MFMA16(kf1, qfB1, z);
                sB[tt] = z;
            }
            if (t == tdiag) {
                int qabA = qw + lrow;
                int qabB = qabA + 16;
                int k00 = t * 64 + g * 4;
#pragma unroll
                for (int tt = 0; tt < 4; ++tt)
#pragma unroll
                    for (int r = 0; r < 4; ++r) {
                        int kab = k00 + tt * 16 + r;
                        if (kab > qabA) sA[tt][r] = -1e30f;
                        if (kab > qabB) sB[tt][r] = -1e30f;
                    }
            }
            SOFTMAX(sA, mA, lA, oA, PsA);
            SOFTMAX(sB, mB, lB, oB, PsBf);
#pragma unroll
            for (int chk = 0; chk < 2; ++chk) {
                f16x8 pfA = *(const f16x8*)&PsA[lrow * 64 + ((chk * 32 + g * 8) ^ swl)];
                f16x8 pfB = *(const f16x8*)&PsBf[lrow * 64 + ((chk * 32 + g * 8) ^ swl)];
#pragma unroll
                for (int dt = 0; dt < 4; ++dt) {
                    f16x8 vf = *(const f16x8*)&Vt[(dt * 16 + lrow) * 64 + ((chk * 32 + g * 8) ^ swl)];
                    oA[dt] = MFMA16(pfA, vf, oA[dt]);
                    oB[dt] = MFMA16(pfB, vf, oB[dt]);
                }
            }
        }
        if (hasnext) {
            int nb = cur ^ 1;
            *(f16x8*)&KsB[nb][skr * 64 + (skc ^ swk)]       = kn0;
            *(f16x8*)&KsB[nb][skr * 64 + ((skc + 8) ^ swk)] = kn1;
#pragma unroll
            for (int j = 0; j < 8; ++j) {
                VtB[nb][(wid * 16 + j) * 64 + (lane ^ (j << 3))]     = vn0[j];
                VtB[nb][(wid * 16 + 8 + j) * 64 + (lane ^ (j << 3))] = vn1[j];
            }
        }
        __syncthreads();
    }
    // finish deferred row-sums
    lA += __shfl_xor(lA, 16); lA += __shfl_xor(lA, 32);
    lB += __shfl_xor(lB, 16); lB += __shfl_xor(lB, 32);

    if (nch == 1) {
#pragma unroll
        for (int rr = 0; rr < 4; ++rr) {
            float invA = 1.f / __shfl(lA, g * 4 + rr);
            float invB = 1.f / __shfl(lB, g * 4 + rr);
            size_t rowA = (size_t)(b * T + qw + g * 4 + rr) * 1024 + h * 64;
#pragma unroll
            for (int dt = 0; dt < 4; ++dt) {
                ao[rowA + dt * 16 + lrow]              = (f16)(oA[dt][rr] * invA);
                ao[rowA + 16 * 1024 + dt * 16 + lrow]  = (f16)(oB[dt][rr] * invB);
            }
        }
    } else {
        char* slot = partial + ((size_t)(bh * 8 + (p - 8)) * 2 + ch) * 17408;
        f16* op = (f16*)slot;
        float* mp = (float*)(slot + 16384);
        float* lp = mp + 128;
#pragma unroll
        for (int rr = 0; rr < 4; ++rr) {
            int rowA = wid * 32 + g * 4 + rr;
#pragma unroll
            for (int dt = 0; dt < 4; ++dt) {
                op[rowA * 64 + dt * 16 + lrow]        = (f16)oA[dt][rr];
                op[(rowA + 16) * 64 + dt * 16 + lrow] = (f16)oB[dt][rr];
            }
        }
        if (g == 0) {
            mp[wid * 32 + lrow]      = mA; lp[wid * 32 + lrow]      = lA;
            mp[wid * 32 + 16 + lrow] = mB; lp[wid * 32 + 16 + lrow] = lB;
        }
    }
}

// ---------------- combine partials (2 chunks) for p>=8, 128 rows ----------------
__global__ __launch_bounds__(256) void combine_kernel(const char* __restrict__ partial, f16* __restrict__ ao)
{
    constexpr int T = 2048;
    int p = 8 + blockIdx.x, bh = blockIdx.y;
    int b = bh >> 4, h = bh & 15;
    int tid = threadIdx.x;
    int row = tid >> 1, dp = (tid & 1) * 32;
    const char* s0 = partial + ((size_t)(bh * 8 + (p - 8)) * 2) * 17408;
    const char* s1 = s0 + 17408;
    const f16* o0 = (const f16*)s0; const float* m0 = (const float*)(s0 + 16384); const float* l0 = m0 + 128;
    const f16* o1 = (const f16*)s1; const float* m1 = (const float*)(s1 + 16384); const float* l1 = m1 + 128;
    float mm0 = m0[row], mm1 = m1[row];
    float M = fmaxf(mm0, mm1);
    float a0 = exp2f(mm0 - M), a1 = exp2f(mm1 - M);
    float inv = 1.f / (l0[row] * a0 + l1[row] * a1);
    const f16* pa = o0 + row * 64 + dp;
    const f16* pb = o1 + row * 64 + dp;
    f16* dst = ao + (size_t)(b * T + p * 128 + row) * 1024 + h * 64 + dp;
#pragma unroll
    for (int vblk = 0; vblk < 4; ++vblk) {
        f16x8 u = ((const f16x8*)pa)[vblk];
        f16x8 w = ((const f16x8*)pb)[vblk];
        f16x8 r;
#pragma unroll
        for (int j = 0; j < 8; ++j)
            r[j] = (f16)(((float)u[j] * a0 + (float)w[j] * a1) * inv);
        ((f16x8*)dst)[vblk] = r;
    }
}

extern "C" void kernel_launch(void* const* d_in, const int* in_sizes, int n_in,
                              void* d_out, int out_size, void* d_ws, size_t ws_size,
                              hipStream_t stream)
{
    (void)in_sizes; (void)n_in; (void)out_size; (void)ws_size;
    const float* x  = (const float*)d_in[0];
    const float* Wq = (const float*)d_in[1];
    const float* Wk = (const float*)d_in[2];
    const float* Wv = (const float*)d_in[3];
    const float* Wo = (const float*)d_in[4];
    float* out = (float*)d_out;

    char* w = (char*)d_ws;
    size_t off = 0;
    auto alloc = [&](size_t bytes) -> void* {
        void* p = (void*)(w + off);
        off += (bytes + 255) & ~(size_t)255;
        return p;
    };
    f16* xb    = (f16*)alloc(4194304ull * 2);    // x f16 [4096,1024] (reused as attn partial buffer)
    f16* WallT = (f16*)alloc(1179648ull * 2);    // [1152,1024] = (Wq|Wk_perm|Wv)^T (partial overflow)
    f16* WoT   = (f16*)alloc(1048576ull * 2);    // Wo^T [1024,1024]
    f16* qg    = (f16*)alloc(4194304ull * 2);    // q proj [4096,1024] (rope fused in attn)
    f16* krp   = (f16*)alloc(262144ull * 2);     // rope'd k [4096,64]
    f16* vg    = (f16*)alloc(262144ull * 2);     // v [4096,64]
    f16* ao    = (f16*)alloc(4194304ull * 2);    // attn out [4096,1024]
    // partial: 512 slots x 17408B = 8.91MB, aliases xb+WallT (dead after QKV GEMM; WoT untouched)
    char* partial = (char*)xb;

    cvt_all_kernel<<<4640, 256, 0, stream>>>(x, Wq, Wk, Wv, Wo, xb, WallT, WoT);
    gemm_bt<0><<<576, 256, 0, stream>>>(xb, WallT, qg, krp, vg, 18);
    attn_kernel<<<dim3(24, 32), 256, 0, stream>>>(qg, krp, vg, ao, partial);
    combine_kernel<<<dim3(8, 32), 256, 0, stream>>>(partial, ao);
    gemm_bt<1><<<512, 256, 0, stream>>>(ao, WoT, out, nullptr, nullptr, 16);
}